// Round 1
// baseline (8731.284 us; speedup 1.0000x reference)
//
#include <hip/hip_runtime.h>

#define NN 50000
#define NE 800000
#define D 256
#define DOUT 128

// ---------------- degree ----------------
__global__ void deg_kernel(const int* __restrict__ dst, float* __restrict__ deg, int E) {
    int e = blockIdx.x * blockDim.x + threadIdx.x;
    if (e < E) atomicAdd(&deg[dst[e]], 1.0f);
}

__global__ void invd_kernel(float* __restrict__ deg, int n) {
    int i = blockIdx.x * blockDim.x + threadIdx.x;
    if (i < n) deg[i] = 1.0f / fmaxf(deg[i], 1.0f);
}

// ---------------- scatter-add of neighbor features ----------------
// one 64-lane group per edge; each lane handles 4 consecutive floats (float4 read, 4 atomics)
__global__ void scatter_kernel(const float* __restrict__ h,
                               const int* __restrict__ src,
                               const int* __restrict__ dst,
                               float* __restrict__ agg, int E) {
    long long t = (long long)blockIdx.x * blockDim.x + threadIdx.x;
    int e = (int)(t >> 6);
    int c = (int)(t & 63);
    if (e >= E) return;
    int s = src[e];
    int d = dst[e];
    const float4 v = *reinterpret_cast<const float4*>(h + (size_t)s * D + c * 4);
    float* p = agg + (size_t)d * D + c * 4;
    atomicAdd(p + 0, v.x);
    atomicAdd(p + 1, v.y);
    atomicAdd(p + 2, v.z);
    atomicAdd(p + 3, v.w);
}

// ---------------- fused GEMM ----------------
// out[n][j] = (RELU?relu:id)( bias[j] + sum_k A0s[n][k]*B0[k][j] (+ sum_k A1[n][k]*B1[k][j] if DUAL) )
// where A0s[n][k] = A0[n][k] * (SCALE ? invd[n] : 1)
// K per matrix fixed at 256. Tile: 64 rows x 64 cols, BK=32, 256 threads, 4x4 micro-tile.
template <bool DUAL, bool RELU, bool SCALE>
__global__ __launch_bounds__(256) void gemm_kernel(
    const float* __restrict__ A0, const float* __restrict__ A1,
    const float* __restrict__ B0, const float* __restrict__ B1,
    const float* __restrict__ bias, const float* __restrict__ invd,
    float* __restrict__ out, int N, int ncol)
{
    __shared__ float Ast[32][68]; // [k][row], padded: 68*4B=272B row stride (16B aligned)
    __shared__ float Bs[32][68];  // [k][col]

    const int tid = threadIdx.x;
    const int r0 = blockIdx.x * 64;
    const int c0 = blockIdx.y * 64;

    const int arl = tid >> 2;               // 0..63 : row within tile for A staging
    const int arow = min(r0 + arl, N - 1);  // clamp OOB rows (writes are guarded)
    const int kc4 = (tid & 3) * 4;          // 0,4,8,12
    const int brow = tid >> 4;              // 0..15
    const int bcol = (tid & 15) * 4;        // 0..60

    float acc[4][4];
    #pragma unroll
    for (int i = 0; i < 4; ++i)
        #pragma unroll
        for (int j = 0; j < 4; ++j) acc[i][j] = 0.0f;

    const int NT = DUAL ? 16 : 8;
    for (int kt = 0; kt < NT; ++kt) {
        const bool second = DUAL && (kt >= 8);
        const float* A = second ? A1 : A0;
        const float* B = second ? B1 : B0;
        const int kbase = (second ? (kt - 8) : kt) * 32;
        const float sc = (SCALE && !second) ? invd[arow] : 1.0f;

        #pragma unroll
        for (int h2 = 0; h2 < 2; ++h2) {
            const int kl = h2 * 16 + kc4;
            const float4 v = *reinterpret_cast<const float4*>(A + (size_t)arow * 256 + kbase + kl);
            Ast[kl + 0][arl] = v.x * sc;
            Ast[kl + 1][arl] = v.y * sc;
            Ast[kl + 2][arl] = v.z * sc;
            Ast[kl + 3][arl] = v.w * sc;
        }
        #pragma unroll
        for (int h2 = 0; h2 < 2; ++h2) {
            const int kk = h2 * 16 + brow;
            const float4 v = *reinterpret_cast<const float4*>(B + (size_t)(kbase + kk) * ncol + c0 + bcol);
            *reinterpret_cast<float4*>(&Bs[kk][bcol]) = v;
        }
        __syncthreads();

        #pragma unroll
        for (int kk = 0; kk < 32; ++kk) {
            const float4 av = *reinterpret_cast<const float4*>(&Ast[kk][(tid >> 4) * 4]);
            const float4 bv = *reinterpret_cast<const float4*>(&Bs[kk][(tid & 15) * 4]);
            const float a[4] = {av.x, av.y, av.z, av.w};
            const float b[4] = {bv.x, bv.y, bv.z, bv.w};
            #pragma unroll
            for (int i = 0; i < 4; ++i)
                #pragma unroll
                for (int j = 0; j < 4; ++j)
                    acc[i][j] = fmaf(a[i], b[j], acc[i][j]);
        }
        __syncthreads();
    }

    const float4 bv = *reinterpret_cast<const float4*>(bias + c0 + (tid & 15) * 4);
    const float bb[4] = {bv.x, bv.y, bv.z, bv.w};
    #pragma unroll
    for (int i = 0; i < 4; ++i) {
        const int row = r0 + (tid >> 4) * 4 + i;
        if (row < N) {
            float4 o;
            float t0 = acc[i][0] + bb[0];
            float t1 = acc[i][1] + bb[1];
            float t2 = acc[i][2] + bb[2];
            float t3 = acc[i][3] + bb[3];
            if (RELU) {
                t0 = fmaxf(t0, 0.0f); t1 = fmaxf(t1, 0.0f);
                t2 = fmaxf(t2, 0.0f); t3 = fmaxf(t3, 0.0f);
            }
            o.x = t0; o.y = t1; o.z = t2; o.w = t3;
            *reinterpret_cast<float4*>(out + (size_t)row * ncol + c0 + (tid & 15) * 4) = o;
        }
    }
}

// ---------------- log-softmax over 128 cols, one wave per row ----------------
__global__ void lsm_kernel(const float* __restrict__ in, float* __restrict__ out, int n) {
    const int wid = (int)(((long long)blockIdx.x * blockDim.x + threadIdx.x) >> 6);
    const int lane = threadIdx.x & 63;
    if (wid >= n) return;
    const float* row = in + (size_t)wid * DOUT;
    const float v0 = row[lane];
    const float v1 = row[lane + 64];
    float m = fmaxf(v0, v1);
    #pragma unroll
    for (int off = 32; off > 0; off >>= 1) m = fmaxf(m, __shfl_xor(m, off));
    float s = expf(v0 - m) + expf(v1 - m);
    #pragma unroll
    for (int off = 32; off > 0; off >>= 1) s += __shfl_xor(s, off);
    const float ls = m + logf(s);
    out[(size_t)wid * DOUT + lane] = v0 - ls;
    out[(size_t)wid * DOUT + lane + 64] = v1 - ls;
}

extern "C" void kernel_launch(void* const* d_in, const int* in_sizes, int n_in,
                              void* d_out, int out_size, void* d_ws, size_t ws_size,
                              hipStream_t stream) {
    const float* x  = (const float*)d_in[0];
    const int* ei   = (const int*)d_in[1];   // [2][NE], int32 per harness convention
    const float* wl = (const float*)d_in[2]; // [3][256][256]
    const float* bl = (const float*)d_in[3]; // [3][256]
    const float* wr = (const float*)d_in[4]; // [3][256][256]
    const float* w1 = (const float*)d_in[5]; // [256][256]
    const float* b1 = (const float*)d_in[6];
    const float* w2 = (const float*)d_in[7]; // [256][128]
    const float* b2 = (const float*)d_in[8];
    const int* src = ei;
    const int* dst = ei + NE;

    // workspace layout: hA | hB | agg | invd   (~154 MB)
    float* hA   = (float*)d_ws;
    float* hB   = hA + (size_t)NN * D;
    float* agg  = hB + (size_t)NN * D;
    float* invd = agg + (size_t)NN * D;
    float* outf = (float*)d_out;

    hipMemsetAsync(invd, 0, NN * sizeof(float), stream);
    deg_kernel<<<(NE + 255) / 256, 256, 0, stream>>>(dst, invd, NE);
    invd_kernel<<<(NN + 255) / 256, 256, 0, stream>>>(invd, NN);

    const dim3 g256((NN + 63) / 64, 4);
    const dim3 g128((NN + 63) / 64, 2);
    const long long st = (long long)NE * 64;
    const int sblocks = (int)((st + 255) / 256);

    const float* hin = x;
    float* hout = hA;
    for (int l = 0; l < 3; ++l) {
        hipMemsetAsync(agg, 0, (size_t)NN * D * sizeof(float), stream);
        scatter_kernel<<<sblocks, 256, 0, stream>>>(hin, src, dst, agg, NE);
        gemm_kernel<true, true, true><<<g256, 256, 0, stream>>>(
            agg, hin, wl + (size_t)l * D * D, wr + (size_t)l * D * D,
            bl + (size_t)l * D, invd, hout, NN, D);
        hin = hout;
        hout = (hout == hA) ? hB : hA;
    }
    // hin == hA here, hout == hB
    gemm_kernel<false, false, false><<<g256, 256, 0, stream>>>(
        hin, nullptr, w1, nullptr, b1, nullptr, hout, NN, D);
    gemm_kernel<false, false, false><<<g128, 256, 0, stream>>>(
        hout, nullptr, w2, nullptr, b2, nullptr, agg, NN, DOUT);
    lsm_kernel<<<((long long)NN * 64 + 255) / 256, 256, 0, stream>>>(agg, outf, NN);
}

// Round 2
// 1182.403 us; speedup vs baseline: 7.3844x; 7.3844x over previous
//
#include <hip/hip_runtime.h>

#define NN 50000
#define NE 800000
#define D 256
#define DOUT 128

// ---------------- int degree ----------------
__global__ void deg_kernel(const int* __restrict__ dst, int* __restrict__ deg, int E) {
    int e = blockIdx.x * blockDim.x + threadIdx.x;
    if (e < E) atomicAdd(&deg[dst[e]], 1);
}

__global__ void invd_kernel(const int* __restrict__ deg, float* __restrict__ invd, int n) {
    int i = blockIdx.x * blockDim.x + threadIdx.x;
    if (i < n) invd[i] = 1.0f / fmaxf((float)deg[i], 1.0f);
}

// ---------------- exclusive scan over degrees -> row_ptr[0..n] (single block) ----------------
__global__ __launch_bounds__(1024) void scan_kernel(const int* __restrict__ deg,
                                                    int* __restrict__ row_ptr, int n) {
    __shared__ int part[1024];
    const int tid = threadIdx.x;
    const int per = (n + 1024) / 1024;  // covers n+1 outputs
    const int base = tid * per;
    int s = 0;
    for (int i = 0; i < per; ++i) {
        int idx = base + i;
        if (idx < n) s += deg[idx];
    }
    part[tid] = s;
    __syncthreads();
    // Hillis-Steele inclusive scan
    for (int off = 1; off < 1024; off <<= 1) {
        int v = (tid >= off) ? part[tid - off] : 0;
        __syncthreads();
        part[tid] += v;
        __syncthreads();
    }
    int run = (tid == 0) ? 0 : part[tid - 1];
    for (int i = 0; i < per; ++i) {
        int idx = base + i;
        if (idx <= n) {
            row_ptr[idx] = run;
            if (idx < n) run += deg[idx];
        }
    }
}

// ---------------- CSR fill (atomic cursor; order within a node irrelevant) ----------------
__global__ void fill_kernel(const int* __restrict__ src, const int* __restrict__ dst,
                            const int* __restrict__ row_ptr, int* __restrict__ cursor,
                            int* __restrict__ csr_src, int E) {
    int e = blockIdx.x * blockDim.x + threadIdx.x;
    if (e < E) {
        int d = dst[e];
        int pos = atomicAdd(&cursor[d], 1);
        csr_src[row_ptr[d] + pos] = src[e];
    }
}

// ---------------- gather-mean: one wave per node ----------------
__global__ __launch_bounds__(256) void gather_kernel(const float* __restrict__ h,
                                                     const int* __restrict__ csr_src,
                                                     const int* __restrict__ row_ptr,
                                                     const float* __restrict__ invd,
                                                     float* __restrict__ agg, int n) {
    const int node = blockIdx.x * (blockDim.x >> 6) + (threadIdx.x >> 6);
    const int lane = threadIdx.x & 63;
    if (node >= n) return;
    const int beg = row_ptr[node];
    const int end = row_ptr[node + 1];
    float4 acc = {0.0f, 0.0f, 0.0f, 0.0f};
    for (int i = beg; i < end; ++i) {
        const int s = csr_src[i];
        const float4 v = *reinterpret_cast<const float4*>(h + (size_t)s * D + lane * 4);
        acc.x += v.x; acc.y += v.y; acc.z += v.z; acc.w += v.w;
    }
    const float sc = invd[node];
    acc.x *= sc; acc.y *= sc; acc.z *= sc; acc.w *= sc;
    *reinterpret_cast<float4*>(agg + (size_t)node * D + lane * 4) = acc;
}

// ---------------- fused GEMM ----------------
// out[n][j] = (RELU?relu:id)( bias[j] + sum_k A0[n][k]*B0[k][j] (+ sum_k A1[n][k]*B1[k][j] if DUAL) )
// K per matrix fixed at 256. Tile: 64 rows x 64 cols, BK=32, 256 threads, 4x4 micro-tile.
template <bool DUAL, bool RELU>
__global__ __launch_bounds__(256) void gemm_kernel(
    const float* __restrict__ A0, const float* __restrict__ A1,
    const float* __restrict__ B0, const float* __restrict__ B1,
    const float* __restrict__ bias,
    float* __restrict__ out, int N, int ncol)
{
    __shared__ float Ast[32][68]; // [k][row], padded
    __shared__ float Bs[32][68];  // [k][col]

    const int tid = threadIdx.x;
    const int r0 = blockIdx.x * 64;
    const int c0 = blockIdx.y * 64;

    const int arl = tid >> 2;               // 0..63 : row within tile for A staging
    const int arow = min(r0 + arl, N - 1);  // clamp OOB rows (writes are guarded)
    const int kc4 = (tid & 3) * 4;          // 0,4,8,12
    const int brow = tid >> 4;              // 0..15
    const int bcol = (tid & 15) * 4;        // 0..60

    float acc[4][4];
    #pragma unroll
    for (int i = 0; i < 4; ++i)
        #pragma unroll
        for (int j = 0; j < 4; ++j) acc[i][j] = 0.0f;

    const int NT = DUAL ? 16 : 8;
    for (int kt = 0; kt < NT; ++kt) {
        const bool second = DUAL && (kt >= 8);
        const float* A = second ? A1 : A0;
        const float* B = second ? B1 : B0;
        const int kbase = (second ? (kt - 8) : kt) * 32;

        #pragma unroll
        for (int h2 = 0; h2 < 2; ++h2) {
            const int kl = h2 * 16 + kc4;
            const float4 v = *reinterpret_cast<const float4*>(A + (size_t)arow * 256 + kbase + kl);
            Ast[kl + 0][arl] = v.x;
            Ast[kl + 1][arl] = v.y;
            Ast[kl + 2][arl] = v.z;
            Ast[kl + 3][arl] = v.w;
        }
        #pragma unroll
        for (int h2 = 0; h2 < 2; ++h2) {
            const int kk = h2 * 16 + brow;
            const float4 v = *reinterpret_cast<const float4*>(B + (size_t)(kbase + kk) * ncol + c0 + bcol);
            *reinterpret_cast<float4*>(&Bs[kk][bcol]) = v;
        }
        __syncthreads();

        #pragma unroll
        for (int kk = 0; kk < 32; ++kk) {
            const float4 av = *reinterpret_cast<const float4*>(&Ast[kk][(tid >> 4) * 4]);
            const float4 bv = *reinterpret_cast<const float4*>(&Bs[kk][(tid & 15) * 4]);
            const float a[4] = {av.x, av.y, av.z, av.w};
            const float b[4] = {bv.x, bv.y, bv.z, bv.w};
            #pragma unroll
            for (int i = 0; i < 4; ++i)
                #pragma unroll
                for (int j = 0; j < 4; ++j)
                    acc[i][j] = fmaf(a[i], b[j], acc[i][j]);
        }
        __syncthreads();
    }

    const float4 bv = *reinterpret_cast<const float4*>(bias + c0 + (tid & 15) * 4);
    const float bb[4] = {bv.x, bv.y, bv.z, bv.w};
    #pragma unroll
    for (int i = 0; i < 4; ++i) {
        const int row = r0 + (tid >> 4) * 4 + i;
        if (row < N) {
            float4 o;
            float t0 = acc[i][0] + bb[0];
            float t1 = acc[i][1] + bb[1];
            float t2 = acc[i][2] + bb[2];
            float t3 = acc[i][3] + bb[3];
            if (RELU) {
                t0 = fmaxf(t0, 0.0f); t1 = fmaxf(t1, 0.0f);
                t2 = fmaxf(t2, 0.0f); t3 = fmaxf(t3, 0.0f);
            }
            o.x = t0; o.y = t1; o.z = t2; o.w = t3;
            *reinterpret_cast<float4*>(out + (size_t)row * ncol + c0 + (tid & 15) * 4) = o;
        }
    }
}

// ---------------- log-softmax over 128 cols, one wave per row ----------------
__global__ void lsm_kernel(const float* __restrict__ in, float* __restrict__ out, int n) {
    const int wid = (int)(((long long)blockIdx.x * blockDim.x + threadIdx.x) >> 6);
    const int lane = threadIdx.x & 63;
    if (wid >= n) return;
    const float* row = in + (size_t)wid * DOUT;
    const float v0 = row[lane];
    const float v1 = row[lane + 64];
    float m = fmaxf(v0, v1);
    #pragma unroll
    for (int off = 32; off > 0; off >>= 1) m = fmaxf(m, __shfl_xor(m, off));
    float s = expf(v0 - m) + expf(v1 - m);
    #pragma unroll
    for (int off = 32; off > 0; off >>= 1) s += __shfl_xor(s, off);
    const float ls = m + logf(s);
    out[(size_t)wid * DOUT + lane] = v0 - ls;
    out[(size_t)wid * DOUT + lane + 64] = v1 - ls;
}

extern "C" void kernel_launch(void* const* d_in, const int* in_sizes, int n_in,
                              void* d_out, int out_size, void* d_ws, size_t ws_size,
                              hipStream_t stream) {
    const float* x  = (const float*)d_in[0];
    const int* ei   = (const int*)d_in[1];   // [2][NE] int32
    const float* wl = (const float*)d_in[2];
    const float* bl = (const float*)d_in[3];
    const float* wr = (const float*)d_in[4];
    const float* w1 = (const float*)d_in[5];
    const float* b1 = (const float*)d_in[6];
    const float* w2 = (const float*)d_in[7];
    const float* b2 = (const float*)d_in[8];
    const int* src = ei;
    const int* dst = ei + NE;

    // workspace layout
    float* hA   = (float*)d_ws;                       // NN*D
    float* hB   = hA + (size_t)NN * D;                // NN*D
    float* agg  = hB + (size_t)NN * D;                // NN*D
    float* invd = agg + (size_t)NN * D;               // NN
    int* degi     = (int*)(invd + NN);                // NN
    int* row_ptr  = degi + NN;                        // NN+1
    int* cursor   = row_ptr + NN + 1;                 // NN
    int* csr_src  = cursor + NN;                      // NE

    float* outf = (float*)d_out;

    // ---- build CSR (per call; deterministic up to neighbor order) ----
    hipMemsetAsync(degi, 0, NN * sizeof(int), stream);
    hipMemsetAsync(cursor, 0, NN * sizeof(int), stream);
    deg_kernel<<<(NE + 255) / 256, 256, 0, stream>>>(dst, degi, NE);
    invd_kernel<<<(NN + 255) / 256, 256, 0, stream>>>(degi, invd, NN);
    scan_kernel<<<1, 1024, 0, stream>>>(degi, row_ptr, NN);
    fill_kernel<<<(NE + 255) / 256, 256, 0, stream>>>(src, dst, row_ptr, cursor, csr_src, NE);

    const dim3 g256((NN + 63) / 64, 4);
    const dim3 g128((NN + 63) / 64, 2);
    const int gblocks = (NN + 3) / 4;  // 4 waves (nodes) per 256-thread block

    const float* hin = x;
    float* hout = hA;
    for (int l = 0; l < 3; ++l) {
        gather_kernel<<<gblocks, 256, 0, stream>>>(hin, csr_src, row_ptr, invd, agg, NN);
        gemm_kernel<true, true><<<g256, 256, 0, stream>>>(
            agg, hin, wl + (size_t)l * D * D, wr + (size_t)l * D * D,
            bl + (size_t)l * D, hout, NN, D);
        hin = hout;
        hout = (hout == hA) ? hB : hA;
    }
    // hin == hA here, hout == hB
    gemm_kernel<false, false><<<g256, 256, 0, stream>>>(
        hin, nullptr, w1, nullptr, b1, hout, NN, D);
    gemm_kernel<false, false><<<g128, 256, 0, stream>>>(
        hout, nullptr, w2, nullptr, b2, agg, NN, DOUT);
    lsm_kernel<<<((long long)NN * 64 + 255) / 256, 256, 0, stream>>>(agg, outf, NN);
}

// Round 3
// 632.834 us; speedup vs baseline: 13.7971x; 1.8684x over previous
//
#include <hip/hip_runtime.h>

#define NN 50000
#define NE 800000
#define D 256
#define DOUT 128

typedef __attribute__((ext_vector_type(8))) short bf16x8;
typedef __attribute__((ext_vector_type(4))) float f32x4;

__device__ __forceinline__ ushort f2b(float f) {
    union { float f; unsigned u; } v; v.f = f;
    unsigned u = v.u + 0x7fffu + ((v.u >> 16) & 1u);
    return (ushort)(u >> 16);
}
__device__ __forceinline__ float b2f(ushort h) {
    union { unsigned u; float f; } v; v.u = ((unsigned)h) << 16;
    return v.f;
}

// ---------------- CSR build ----------------
__global__ void deg_kernel(const int* __restrict__ dst, int* __restrict__ deg, int E) {
    int e = blockIdx.x * blockDim.x + threadIdx.x;
    if (e < E) atomicAdd(&deg[dst[e]], 1);
}

__global__ void invd_kernel(const int* __restrict__ deg, float* __restrict__ invd, int n) {
    int i = blockIdx.x * blockDim.x + threadIdx.x;
    if (i < n) invd[i] = 1.0f / fmaxf((float)deg[i], 1.0f);
}

__global__ __launch_bounds__(1024) void scan_kernel(const int* __restrict__ deg,
                                                    int* __restrict__ row_ptr, int n) {
    __shared__ int part[1024];
    const int tid = threadIdx.x;
    const int per = (n + 1024) / 1024;
    const int base = tid * per;
    int s = 0;
    for (int i = 0; i < per; ++i) {
        int idx = base + i;
        if (idx < n) s += deg[idx];
    }
    part[tid] = s;
    __syncthreads();
    for (int off = 1; off < 1024; off <<= 1) {
        int v = (tid >= off) ? part[tid - off] : 0;
        __syncthreads();
        part[tid] += v;
        __syncthreads();
    }
    int run = (tid == 0) ? 0 : part[tid - 1];
    for (int i = 0; i < per; ++i) {
        int idx = base + i;
        if (idx <= n) {
            row_ptr[idx] = run;
            if (idx < n) run += deg[idx];
        }
    }
}

__global__ void fill_kernel(const int* __restrict__ src, const int* __restrict__ dst,
                            const int* __restrict__ row_ptr, int* __restrict__ cursor,
                            int* __restrict__ csr_src, int E) {
    int e = blockIdx.x * blockDim.x + threadIdx.x;
    if (e < E) {
        int d = dst[e];
        int pos = atomicAdd(&cursor[d], 1);
        csr_src[row_ptr[d] + pos] = src[e];
    }
}

// ---------------- converts ----------------
__global__ void cvt_bf16_kernel(const float* __restrict__ in, ushort* __restrict__ out, int n4) {
    int i = blockIdx.x * blockDim.x + threadIdx.x;
    if (i >= n4) return;
    const float4 v = *reinterpret_cast<const float4*>(in + (size_t)i * 4);
    ushort4 o;
    o.x = f2b(v.x); o.y = f2b(v.y); o.z = f2b(v.z); o.w = f2b(v.w);
    *reinterpret_cast<ushort4*>(out + (size_t)i * 4) = o;
}

// in: [nmat][256][ncol] f32  ->  out: [nmat][ncol][256] bf16 (transposed per matrix)
__global__ void cvt_wt_kernel(const float* __restrict__ in, ushort* __restrict__ out,
                              int nmat, int ncol) {
    int idx = blockIdx.x * blockDim.x + threadIdx.x;
    int total = nmat * 256 * ncol;
    if (idx >= total) return;
    int k = idx & 255;
    int t = idx >> 8;       // m*ncol + n
    int n = t % ncol;
    int m = t / ncol;
    out[idx] = f2b(in[(size_t)m * 256 * ncol + (size_t)k * ncol + n]);
}

// ---------------- gather-mean (bf16 in/out, fp32 accum): one wave per node ----------------
__global__ __launch_bounds__(256) void gather_kernel(const ushort* __restrict__ h,
                                                     const int* __restrict__ csr_src,
                                                     const int* __restrict__ row_ptr,
                                                     const float* __restrict__ invd,
                                                     ushort* __restrict__ agg, int n) {
    const int node = blockIdx.x * 4 + (threadIdx.x >> 6);
    const int lane = threadIdx.x & 63;
    if (node >= n) return;
    const int beg = row_ptr[node];
    const int end = row_ptr[node + 1];
    float a0 = 0.f, a1 = 0.f, a2 = 0.f, a3 = 0.f;
    for (int i = beg; i < end; ++i) {
        const int s = csr_src[i];
        const ushort4 v = *reinterpret_cast<const ushort4*>(h + (size_t)s * D + lane * 4);
        a0 += b2f(v.x); a1 += b2f(v.y); a2 += b2f(v.z); a3 += b2f(v.w);
    }
    const float sc = invd[node];
    ushort4 o;
    o.x = f2b(a0 * sc); o.y = f2b(a1 * sc); o.z = f2b(a2 * sc); o.w = f2b(a3 * sc);
    *reinterpret_cast<ushort4*>(agg + (size_t)node * D + lane * 4) = o;
}

// ---------------- bf16 MFMA GEMM ----------------
// out[n][j] = epi( bias[j] + sum_k A0[n][k]*B0T[j][k] (+ sum_k A1[n][k]*B1T[j][k] if DUAL) )
// A: [N][256] bf16 row-major. BT: [ncol][256] bf16 (i.e. B transposed, K-contiguous).
// Tile 128x128, 4 waves (2x2), wave computes 64x64 via 4x4 fragments of 16x16x32.
template <bool DUAL, bool RELU, bool OUTBF>
__global__ __launch_bounds__(256) void mgemm_kernel(
    const ushort* __restrict__ A0, const ushort* __restrict__ A1,
    const ushort* __restrict__ B0T, const ushort* __restrict__ B1T,
    const float* __restrict__ bias, void* __restrict__ out, int N, int ncol)
{
    __shared__ ushort As[128][40];  // 80 B row stride: 16B-aligned, ~2-way bank alias (free)
    __shared__ ushort Bs[128][40];

    const int tid = threadIdx.x;
    const int wave = tid >> 6;
    const int lane = tid & 63;
    const int wm = wave >> 1;
    const int wn = wave & 1;
    const int l15 = lane & 15;
    const int l4 = lane >> 4;
    const int r0 = blockIdx.x * 128;
    const int c0 = blockIdx.y * 128;

    const f32x4 zero = {0.f, 0.f, 0.f, 0.f};
    f32x4 acc[4][4];
    #pragma unroll
    for (int i = 0; i < 4; ++i)
        #pragma unroll
        for (int j = 0; j < 4; ++j) acc[i][j] = zero;

    const int NT = DUAL ? 16 : 8;
    for (int kt = 0; kt < NT; ++kt) {
        const bool second = DUAL && (kt >= 8);
        const ushort* A = second ? A1 : A0;
        const ushort* BT = second ? B1T : B0T;
        const int kb = (second ? (kt - 8) : kt) * 32;

        // stage A rows r0..r0+127 cols kb..kb+31, B^T rows c0..c0+127 cols kb..kb+31
        #pragma unroll
        for (int it = 0; it < 2; ++it) {
            const int idx = it * 256 + tid;
            const int rr = idx >> 2;       // 0..127
            const int ch = (idx & 3) * 8;  // 0,8,16,24 (bf16 elems)
            const int grow = min(r0 + rr, N - 1);
            const float4 va = *reinterpret_cast<const float4*>(A + (size_t)grow * 256 + kb + ch);
            *reinterpret_cast<float4*>(&As[rr][ch]) = va;
            const float4 vb = *reinterpret_cast<const float4*>(BT + (size_t)(c0 + rr) * 256 + kb + ch);
            *reinterpret_cast<float4*>(&Bs[rr][ch]) = vb;
        }
        __syncthreads();

        bf16x8 af[4], bfr[4];
        #pragma unroll
        for (int i = 0; i < 4; ++i)
            af[i] = *reinterpret_cast<const bf16x8*>(&As[wm * 64 + 16 * i + l15][l4 * 8]);
        #pragma unroll
        for (int j = 0; j < 4; ++j)
            bfr[j] = *reinterpret_cast<const bf16x8*>(&Bs[wn * 64 + 16 * j + l15][l4 * 8]);
        #pragma unroll
        for (int i = 0; i < 4; ++i)
            #pragma unroll
            for (int j = 0; j < 4; ++j)
                acc[i][j] = __builtin_amdgcn_mfma_f32_16x16x32_bf16(af[i], bfr[j], acc[i][j], 0, 0, 0);
        __syncthreads();
    }

    // epilogue: bias + (relu) + store (C/D layout: col=lane&15, row=(lane>>4)*4+reg)
    const int rbase = r0 + wm * 64;
    const int cbase = c0 + wn * 64;
    #pragma unroll
    for (int i = 0; i < 4; ++i) {
        #pragma unroll
        for (int r = 0; r < 4; ++r) {
            const int row = rbase + 16 * i + l4 * 4 + r;
            if (row < N) {
                #pragma unroll
                for (int j = 0; j < 4; ++j) {
                    const int col = cbase + 16 * j + l15;
                    float v = acc[i][j][r] + bias[col];
                    if (RELU) v = fmaxf(v, 0.f);
                    if (OUTBF)
                        ((ushort*)out)[(size_t)row * ncol + col] = f2b(v);
                    else
                        ((float*)out)[(size_t)row * ncol + col] = v;
                }
            }
        }
    }
}

// ---------------- log-softmax over 128 cols, one wave per row ----------------
__global__ void lsm_kernel(const float* __restrict__ in, float* __restrict__ out, int n) {
    const int wid = (int)(((long long)blockIdx.x * blockDim.x + threadIdx.x) >> 6);
    const int lane = threadIdx.x & 63;
    if (wid >= n) return;
    const float* row = in + (size_t)wid * DOUT;
    const float v0 = row[lane];
    const float v1 = row[lane + 64];
    float m = fmaxf(v0, v1);
    #pragma unroll
    for (int off = 32; off > 0; off >>= 1) m = fmaxf(m, __shfl_xor(m, off));
    float s = expf(v0 - m) + expf(v1 - m);
    #pragma unroll
    for (int off = 32; off > 0; off >>= 1) s += __shfl_xor(s, off);
    const float ls = m + logf(s);
    out[(size_t)wid * DOUT + lane] = v0 - ls;
    out[(size_t)wid * DOUT + lane + 64] = v1 - ls;
}

extern "C" void kernel_launch(void* const* d_in, const int* in_sizes, int n_in,
                              void* d_out, int out_size, void* d_ws, size_t ws_size,
                              hipStream_t stream) {
    const float* x  = (const float*)d_in[0];
    const int* ei   = (const int*)d_in[1];   // [2][NE] int32
    const float* wl = (const float*)d_in[2];
    const float* bl = (const float*)d_in[3];
    const float* wr = (const float*)d_in[4];
    const float* w1 = (const float*)d_in[5];
    const float* b1 = (const float*)d_in[6];
    const float* w2 = (const float*)d_in[7];
    const float* b2 = (const float*)d_in[8];
    const int* src = ei;
    const int* dst = ei + NE;

    // ---- workspace layout ----
    ushort* hx   = (ushort*)d_ws;                 // NN*D
    ushort* hA   = hx + (size_t)NN * D;           // NN*D
    ushort* hB   = hA + (size_t)NN * D;           // NN*D
    ushort* aggb = hB + (size_t)NN * D;           // NN*D
    ushort* wlT  = aggb + (size_t)NN * D;         // 3*256*256
    ushort* wrT  = wlT + 3 * 256 * 256;           // 3*256*256
    ushort* w1T  = wrT + 3 * 256 * 256;           // 256*256
    ushort* w2T  = w1T + 256 * 256;               // 128*256
    float* mp2o  = (float*)(w2T + 128 * 256);     // NN*DOUT
    float* invd  = mp2o + (size_t)NN * DOUT;      // NN
    int* degi    = (int*)(invd + NN);             // NN
    int* row_ptr = degi + NN;                     // NN+1
    int* cursor  = row_ptr + NN + 1;              // NN
    int* csr_src = cursor + NN;                   // NE
    float* outf  = (float*)d_out;

    // ---- CSR build ----
    hipMemsetAsync(degi, 0, NN * sizeof(int), stream);
    hipMemsetAsync(cursor, 0, NN * sizeof(int), stream);
    deg_kernel<<<(NE + 255) / 256, 256, 0, stream>>>(dst, degi, NE);
    invd_kernel<<<(NN + 255) / 256, 256, 0, stream>>>(degi, invd, NN);
    scan_kernel<<<1, 1024, 0, stream>>>(degi, row_ptr, NN);
    fill_kernel<<<(NE + 255) / 256, 256, 0, stream>>>(src, dst, row_ptr, cursor, csr_src, NE);

    // ---- converts ----
    cvt_bf16_kernel<<<(NN * D / 4 + 255) / 256, 256, 0, stream>>>(x, hx, NN * D / 4);
    cvt_wt_kernel<<<(3 * 256 * 256 + 255) / 256, 256, 0, stream>>>(wl, wlT, 3, 256);
    cvt_wt_kernel<<<(3 * 256 * 256 + 255) / 256, 256, 0, stream>>>(wr, wrT, 3, 256);
    cvt_wt_kernel<<<(256 * 256 + 255) / 256, 256, 0, stream>>>(w1, w1T, 1, 256);
    cvt_wt_kernel<<<(128 * 256 + 255) / 256, 256, 0, stream>>>(w2, w2T, 1, 128);

    const dim3 g2((NN + 127) / 128, 2);
    const dim3 g1((NN + 127) / 128, 1);

    const ushort* hin = hx;
    ushort* hout = hA;
    for (int l = 0; l < 3; ++l) {
        gather_kernel<<<(NN + 3) / 4, 256, 0, stream>>>(hin, csr_src, row_ptr, invd, aggb, NN);
        mgemm_kernel<true, true, true><<<g2, 256, 0, stream>>>(
            aggb, hin, wlT + (size_t)l * 256 * 256, wrT + (size_t)l * 256 * 256,
            bl + (size_t)l * 256, hout, NN, 256);
        hin = hout;
        hout = (hout == hA) ? hB : hA;
    }
    // hin == hA, hout == hB
    mgemm_kernel<false, false, true><<<g2, 256, 0, stream>>>(
        hin, nullptr, w1T, nullptr, b1, hB, NN, 256);
    mgemm_kernel<false, false, false><<<g1, 256, 0, stream>>>(
        hB, nullptr, w2T, nullptr, b2, mp2o, NN, 128);
    lsm_kernel<<<((long long)NN * 64 + 255) / 256, 256, 0, stream>>>(mp2o, outf, NN);
}

// Round 4
// 465.788 us; speedup vs baseline: 18.7452x; 1.3586x over previous
//
#include <hip/hip_runtime.h>

#define NN 50000
#define NE 800000
#define D 256
#define DOUT 128

typedef __attribute__((ext_vector_type(8))) short bf16x8;
typedef __attribute__((ext_vector_type(8))) ushort u16x8;
typedef __attribute__((ext_vector_type(4))) float f32x4;

__device__ __forceinline__ ushort f2b(float f) {
    union { float f; unsigned u; } v; v.f = f;
    unsigned u = v.u + 0x7fffu + ((v.u >> 16) & 1u);
    return (ushort)(u >> 16);
}
__device__ __forceinline__ float b2f(ushort h) {
    union { unsigned u; float f; } v; v.u = ((unsigned)h) << 16;
    return v.f;
}

// ---------------- CSR build ----------------
__global__ void deg_kernel(const int* __restrict__ dst, int* __restrict__ deg, int E) {
    int e = blockIdx.x * blockDim.x + threadIdx.x;
    if (e < E) atomicAdd(&deg[dst[e]], 1);
}

__global__ void invd_kernel(const int* __restrict__ deg, float* __restrict__ invd, int n) {
    int i = blockIdx.x * blockDim.x + threadIdx.x;
    if (i < n) invd[i] = 1.0f / fmaxf((float)deg[i], 1.0f);
}

// phase A: per-block sums of deg
__global__ __launch_bounds__(256) void scanA_kernel(const int* __restrict__ deg,
                                                    int* __restrict__ blk, int n) {
    __shared__ int red[4];
    const int i = blockIdx.x * 256 + threadIdx.x;
    int v = (i < n) ? deg[i] : 0;
    #pragma unroll
    for (int off = 32; off > 0; off >>= 1) v += __shfl_xor(v, off);
    if ((threadIdx.x & 63) == 0) red[threadIdx.x >> 6] = v;
    __syncthreads();
    if (threadIdx.x == 0) blk[blockIdx.x] = red[0] + red[1] + red[2] + red[3];
}

// phase B: exclusive scan of block sums (nb <= 256), single block
__global__ __launch_bounds__(256) void scanB_kernel(int* __restrict__ blk, int nb) {
    __shared__ int s[256];
    const int t = threadIdx.x;
    const int v = (t < nb) ? blk[t] : 0;
    s[t] = v;
    __syncthreads();
    for (int off = 1; off < 256; off <<= 1) {
        int u = (t >= off) ? s[t - off] : 0;
        __syncthreads();
        s[t] += u;
        __syncthreads();
    }
    if (t < nb) blk[t] = s[t] - v;  // exclusive
}

// phase C: row_ptr[i] = blk_off[b] + exclusive-scan-within-block
__global__ __launch_bounds__(256) void scanC_kernel(const int* __restrict__ deg,
                                                    const int* __restrict__ blk,
                                                    int* __restrict__ row_ptr, int n) {
    __shared__ int s[256];
    const int t = threadIdx.x;
    const int i = blockIdx.x * 256 + t;
    const int v = (i < n) ? deg[i] : 0;
    s[t] = v;
    __syncthreads();
    for (int off = 1; off < 256; off <<= 1) {
        int u = (t >= off) ? s[t - off] : 0;
        __syncthreads();
        s[t] += u;
        __syncthreads();
    }
    if (i <= n) row_ptr[i] = blk[blockIdx.x] + s[t] - v;
}

__global__ void fill_kernel(const int* __restrict__ src, const int* __restrict__ dst,
                            const int* __restrict__ row_ptr, int* __restrict__ cursor,
                            int* __restrict__ csr_src, int E) {
    int e = blockIdx.x * blockDim.x + threadIdx.x;
    if (e < E) {
        int d = dst[e];
        int pos = atomicAdd(&cursor[d], 1);
        csr_src[row_ptr[d] + pos] = src[e];
    }
}

// ---------------- converts ----------------
__global__ void cvt_bf16_kernel(const float* __restrict__ in, ushort* __restrict__ out, int n4) {
    int i = blockIdx.x * blockDim.x + threadIdx.x;
    if (i >= n4) return;
    const float4 v = *reinterpret_cast<const float4*>(in + (size_t)i * 4);
    ushort4 o;
    o.x = f2b(v.x); o.y = f2b(v.y); o.z = f2b(v.z); o.w = f2b(v.w);
    *reinterpret_cast<ushort4*>(out + (size_t)i * 4) = o;
}

// in: [nmat][256][ncol] f32  ->  out: [nmat][ncol][256] bf16 (transposed per matrix)
__global__ void cvt_wt_kernel(const float* __restrict__ in, ushort* __restrict__ out,
                              int nmat, int ncol) {
    int idx = blockIdx.x * blockDim.x + threadIdx.x;
    int total = nmat * 256 * ncol;
    if (idx >= total) return;
    int k = idx & 255;
    int t = idx >> 8;       // m*ncol + n
    int n = t % ncol;
    int m = t / ncol;
    out[idx] = f2b(in[(size_t)m * 256 * ncol + (size_t)k * ncol + n]);
}

// ---------------- gather-mean: one wave per node, 2 neighbors per iteration ----------------
// lane half h=lane>>5 walks neighbor i+h; each lane reads ushort8 (16 B); halves combined via shfl.
__global__ __launch_bounds__(256) void gather_kernel(const ushort* __restrict__ h,
                                                     const int* __restrict__ csr_src,
                                                     const int* __restrict__ row_ptr,
                                                     const float* __restrict__ invd,
                                                     ushort* __restrict__ agg, int n) {
    const int node = blockIdx.x * 4 + (threadIdx.x >> 6);
    const int lane = threadIdx.x & 63;
    if (node >= n) return;
    const int beg = row_ptr[node];
    const int end = row_ptr[node + 1];
    const int half = lane >> 5;
    const int l32 = lane & 31;

    float a[8];
    #pragma unroll
    for (int j = 0; j < 8; ++j) a[j] = 0.f;

    int i = beg;
    for (; i + 1 < end; i += 2) {
        const int s = csr_src[i + half];
        const u16x8 v = *reinterpret_cast<const u16x8*>(h + (size_t)s * D + l32 * 8);
        #pragma unroll
        for (int j = 0; j < 8; ++j) a[j] += b2f(v[j]);
    }
    if (i < end && half == 0) {
        const int s = csr_src[i];
        const u16x8 v = *reinterpret_cast<const u16x8*>(h + (size_t)s * D + l32 * 8);
        #pragma unroll
        for (int j = 0; j < 8; ++j) a[j] += b2f(v[j]);
    }
    // combine the two halves (lane l and l+32 hold the same columns)
    #pragma unroll
    for (int j = 0; j < 8; ++j) a[j] += __shfl_xor(a[j], 32);

    if (half == 0) {
        const float sc = invd[node];
        u16x8 o;
        #pragma unroll
        for (int j = 0; j < 8; ++j) o[j] = f2b(a[j] * sc);
        *reinterpret_cast<u16x8*>(agg + (size_t)node * D + l32 * 8) = o;
    }
}

// ---------------- bf16 MFMA GEMM ----------------
// out[n][j] = epi( bias[j] + sum_k A0[n][k]*B0T[j][k] (+ sum_k A1[n][k]*B1T[j][k] if DUAL) )
// A: [N][256] bf16 row-major. BT: [ncol][256] bf16 (B transposed, K-contiguous).
// Tile 128x128, 4 waves (2x2), wave computes 64x64 via 4x4 fragments of 16x16x32.
template <bool DUAL, bool RELU, bool OUTBF>
__global__ __launch_bounds__(256) void mgemm_kernel(
    const ushort* __restrict__ A0, const ushort* __restrict__ A1,
    const ushort* __restrict__ B0T, const ushort* __restrict__ B1T,
    const float* __restrict__ bias, void* __restrict__ out, int N, int ncol)
{
    __shared__ ushort As[128][40];  // 80 B row stride
    __shared__ ushort Bs[128][40];

    const int tid = threadIdx.x;
    const int wave = tid >> 6;
    const int lane = tid & 63;
    const int wm = wave >> 1;
    const int wn = wave & 1;
    const int l15 = lane & 15;
    const int l4 = lane >> 4;
    const int r0 = blockIdx.x * 128;
    const int c0 = blockIdx.y * 128;

    const f32x4 zero = {0.f, 0.f, 0.f, 0.f};
    f32x4 acc[4][4];
    #pragma unroll
    for (int i = 0; i < 4; ++i)
        #pragma unroll
        for (int j = 0; j < 4; ++j) acc[i][j] = zero;

    const int NT = DUAL ? 16 : 8;
    for (int kt = 0; kt < NT; ++kt) {
        const bool second = DUAL && (kt >= 8);
        const ushort* A = second ? A1 : A0;
        const ushort* BT = second ? B1T : B0T;
        const int kb = (second ? (kt - 8) : kt) * 32;

        #pragma unroll
        for (int it = 0; it < 2; ++it) {
            const int idx = it * 256 + tid;
            const int rr = idx >> 2;       // 0..127
            const int ch = (idx & 3) * 8;  // 0,8,16,24
            const int grow = min(r0 + rr, N - 1);
            const float4 va = *reinterpret_cast<const float4*>(A + (size_t)grow * 256 + kb + ch);
            *reinterpret_cast<float4*>(&As[rr][ch]) = va;
            const float4 vb = *reinterpret_cast<const float4*>(BT + (size_t)(c0 + rr) * 256 + kb + ch);
            *reinterpret_cast<float4*>(&Bs[rr][ch]) = vb;
        }
        __syncthreads();

        bf16x8 af[4], bfr[4];
        #pragma unroll
        for (int i = 0; i < 4; ++i)
            af[i] = *reinterpret_cast<const bf16x8*>(&As[wm * 64 + 16 * i + l15][l4 * 8]);
        #pragma unroll
        for (int j = 0; j < 4; ++j)
            bfr[j] = *reinterpret_cast<const bf16x8*>(&Bs[wn * 64 + 16 * j + l15][l4 * 8]);
        #pragma unroll
        for (int i = 0; i < 4; ++i)
            #pragma unroll
            for (int j = 0; j < 4; ++j)
                acc[i][j] = __builtin_amdgcn_mfma_f32_16x16x32_bf16(af[i], bfr[j], acc[i][j], 0, 0, 0);
        __syncthreads();
    }

    const int rbase = r0 + wm * 64;
    const int cbase = c0 + wn * 64;
    #pragma unroll
    for (int i = 0; i < 4; ++i) {
        #pragma unroll
        for (int r = 0; r < 4; ++r) {
            const int row = rbase + 16 * i + l4 * 4 + r;
            if (row < N) {
                #pragma unroll
                for (int j = 0; j < 4; ++j) {
                    const int col = cbase + 16 * j + l15;
                    float v = acc[i][j][r] + bias[col];
                    if (RELU) v = fmaxf(v, 0.f);
                    if (OUTBF)
                        ((ushort*)out)[(size_t)row * ncol + col] = f2b(v);
                    else
                        ((float*)out)[(size_t)row * ncol + col] = v;
                }
            }
        }
    }
}

// ---------------- log-softmax over 128 cols, one wave per row ----------------
__global__ void lsm_kernel(const float* __restrict__ in, float* __restrict__ out, int n) {
    const int wid = (int)(((long long)blockIdx.x * blockDim.x + threadIdx.x) >> 6);
    const int lane = threadIdx.x & 63;
    if (wid >= n) return;
    const float* row = in + (size_t)wid * DOUT;
    const float v0 = row[lane];
    const float v1 = row[lane + 64];
    float m = fmaxf(v0, v1);
    #pragma unroll
    for (int off = 32; off > 0; off >>= 1) m = fmaxf(m, __shfl_xor(m, off));
    float s = expf(v0 - m) + expf(v1 - m);
    #pragma unroll
    for (int off = 32; off > 0; off >>= 1) s += __shfl_xor(s, off);
    const float ls = m + logf(s);
    out[(size_t)wid * DOUT + lane] = v0 - ls;
    out[(size_t)wid * DOUT + lane + 64] = v1 - ls;
}

extern "C" void kernel_launch(void* const* d_in, const int* in_sizes, int n_in,
                              void* d_out, int out_size, void* d_ws, size_t ws_size,
                              hipStream_t stream) {
    const float* x  = (const float*)d_in[0];
    const int* ei   = (const int*)d_in[1];   // [2][NE] int32
    const float* wl = (const float*)d_in[2];
    const float* bl = (const float*)d_in[3];
    const float* wr = (const float*)d_in[4];
    const float* w1 = (const float*)d_in[5];
    const float* b1 = (const float*)d_in[6];
    const float* w2 = (const float*)d_in[7];
    const float* b2 = (const float*)d_in[8];
    const int* src = ei;
    const int* dst = ei + NE;

    // ---- workspace layout ----
    ushort* hx   = (ushort*)d_ws;                 // NN*D
    ushort* hA   = hx + (size_t)NN * D;           // NN*D
    ushort* hB   = hA + (size_t)NN * D;           // NN*D
    ushort* aggb = hB + (size_t)NN * D;           // NN*D
    ushort* wlT  = aggb + (size_t)NN * D;         // 3*256*256
    ushort* wrT  = wlT + 3 * 256 * 256;           // 3*256*256
    ushort* w1T  = wrT + 3 * 256 * 256;           // 256*256
    ushort* w2T  = w1T + 256 * 256;               // 128*256
    float* mp2o  = (float*)(w2T + 128 * 256);     // NN*DOUT
    float* invd  = mp2o + (size_t)NN * DOUT;      // NN
    int* degi    = (int*)(invd + NN);             // NN
    int* row_ptr = degi + NN;                     // NN+1
    int* cursor  = row_ptr + NN + 1;              // NN
    int* csr_src = cursor + NN;                   // NE
    int* blk     = csr_src + NE;                  // 256
    float* outf  = (float*)d_out;

    const int NB = (NN + 256) / 256;  // 196 blocks: covers NN+1 outputs in phase C

    // ---- CSR build ----
    hipMemsetAsync(degi, 0, NN * sizeof(int), stream);
    hipMemsetAsync(cursor, 0, NN * sizeof(int), stream);
    deg_kernel<<<(NE + 255) / 256, 256, 0, stream>>>(dst, degi, NE);
    invd_kernel<<<(NN + 255) / 256, 256, 0, stream>>>(degi, invd, NN);
    scanA_kernel<<<NB, 256, 0, stream>>>(degi, blk, NN);
    scanB_kernel<<<1, 256, 0, stream>>>(blk, NB);
    scanC_kernel<<<NB, 256, 0, stream>>>(degi, blk, row_ptr, NN);
    fill_kernel<<<(NE + 255) / 256, 256, 0, stream>>>(src, dst, row_ptr, cursor, csr_src, NE);

    // ---- converts ----
    cvt_bf16_kernel<<<(NN * D / 4 + 255) / 256, 256, 0, stream>>>(x, hx, NN * D / 4);
    cvt_wt_kernel<<<(3 * 256 * 256 + 255) / 256, 256, 0, stream>>>(wl, wlT, 3, 256);
    cvt_wt_kernel<<<(3 * 256 * 256 + 255) / 256, 256, 0, stream>>>(wr, wrT, 3, 256);
    cvt_wt_kernel<<<(256 * 256 + 255) / 256, 256, 0, stream>>>(w1, w1T, 1, 256);
    cvt_wt_kernel<<<(128 * 256 + 255) / 256, 256, 0, stream>>>(w2, w2T, 1, 128);

    const dim3 g2((NN + 127) / 128, 2);
    const dim3 g1((NN + 127) / 128, 1);

    const ushort* hin = hx;
    ushort* hout = hA;
    for (int l = 0; l < 3; ++l) {
        gather_kernel<<<(NN + 3) / 4, 256, 0, stream>>>(hin, csr_src, row_ptr, invd, aggb, NN);
        mgemm_kernel<true, true, true><<<g2, 256, 0, stream>>>(
            aggb, hin, wlT + (size_t)l * 256 * 256, wrT + (size_t)l * 256 * 256,
            bl + (size_t)l * 256, hout, NN, 256);
        hin = hout;
        hout = (hout == hA) ? hB : hA;
    }
    // hin == hA, hout == hB
    mgemm_kernel<false, false, true><<<g2, 256, 0, stream>>>(
        hin, nullptr, w1T, nullptr, b1, hB, NN, 256);
    mgemm_kernel<false, false, false><<<g1, 256, 0, stream>>>(
        hB, nullptr, w2T, nullptr, b2, mp2o, NN, 128);
    lsm_kernel<<<((long long)NN * 64 + 255) / 256, 256, 0, stream>>>(mp2o, outf, NN);
}

// Round 5
// 422.062 us; speedup vs baseline: 20.6872x; 1.1036x over previous
//
#include <hip/hip_runtime.h>

#define NN 50000
#define NE 800000
#define D 256
#define DOUT 128

typedef __attribute__((ext_vector_type(8))) short bf16x8;
typedef __attribute__((ext_vector_type(8))) ushort u16x8;
typedef __attribute__((ext_vector_type(4))) float f32x4;

__device__ __forceinline__ ushort f2b(float f) {
    union { float f; unsigned u; } v; v.f = f;
    unsigned u = v.u + 0x7fffu + ((v.u >> 16) & 1u);
    return (ushort)(u >> 16);
}
__device__ __forceinline__ float b2f(ushort h) {
    union { unsigned u; float f; } v; v.u = ((unsigned)h) << 16;
    return v.f;
}

// ---------------- CSR build ----------------
__global__ void deg_kernel(const int* __restrict__ dst, int* __restrict__ deg, int E) {
    int e = blockIdx.x * blockDim.x + threadIdx.x;
    if (e < E) atomicAdd(&deg[dst[e]], 1);
}

__global__ void invd_kernel(const int* __restrict__ deg, float* __restrict__ invd, int n) {
    int i = blockIdx.x * blockDim.x + threadIdx.x;
    if (i < n) invd[i] = 1.0f / fmaxf((float)deg[i], 1.0f);
}

__global__ __launch_bounds__(256) void scanA_kernel(const int* __restrict__ deg,
                                                    int* __restrict__ blk, int n) {
    __shared__ int red[4];
    const int i = blockIdx.x * 256 + threadIdx.x;
    int v = (i < n) ? deg[i] : 0;
    #pragma unroll
    for (int off = 32; off > 0; off >>= 1) v += __shfl_xor(v, off);
    if ((threadIdx.x & 63) == 0) red[threadIdx.x >> 6] = v;
    __syncthreads();
    if (threadIdx.x == 0) blk[blockIdx.x] = red[0] + red[1] + red[2] + red[3];
}

__global__ __launch_bounds__(256) void scanB_kernel(int* __restrict__ blk, int nb) {
    __shared__ int s[256];
    const int t = threadIdx.x;
    const int v = (t < nb) ? blk[t] : 0;
    s[t] = v;
    __syncthreads();
    for (int off = 1; off < 256; off <<= 1) {
        int u = (t >= off) ? s[t - off] : 0;
        __syncthreads();
        s[t] += u;
        __syncthreads();
    }
    if (t < nb) blk[t] = s[t] - v;  // exclusive
}

__global__ __launch_bounds__(256) void scanC_kernel(const int* __restrict__ deg,
                                                    const int* __restrict__ blk,
                                                    int* __restrict__ row_ptr, int n) {
    __shared__ int s[256];
    const int t = threadIdx.x;
    const int i = blockIdx.x * 256 + t;
    const int v = (i < n) ? deg[i] : 0;
    s[t] = v;
    __syncthreads();
    for (int off = 1; off < 256; off <<= 1) {
        int u = (t >= off) ? s[t - off] : 0;
        __syncthreads();
        s[t] += u;
        __syncthreads();
    }
    if (i <= n) row_ptr[i] = blk[blockIdx.x] + s[t] - v;
}

__global__ void fill_kernel(const int* __restrict__ src, const int* __restrict__ dst,
                            const int* __restrict__ row_ptr, int* __restrict__ cursor,
                            int* __restrict__ csr_src, int E) {
    int e = blockIdx.x * blockDim.x + threadIdx.x;
    if (e < E) {
        int d = dst[e];
        int pos = atomicAdd(&cursor[d], 1);
        csr_src[row_ptr[d] + pos] = src[e];
    }
}

// ---------------- converts ----------------
__global__ void cvt_bf16_kernel(const float* __restrict__ in, ushort* __restrict__ out, int n4) {
    int i = blockIdx.x * blockDim.x + threadIdx.x;
    if (i >= n4) return;
    const float4 v = *reinterpret_cast<const float4*>(in + (size_t)i * 4);
    ushort4 o;
    o.x = f2b(v.x); o.y = f2b(v.y); o.z = f2b(v.z); o.w = f2b(v.w);
    *reinterpret_cast<ushort4*>(out + (size_t)i * 4) = o;
}

// in: [nmat][256][ncol] f32  ->  out: [nmat][ncol][256] bf16 (transposed per matrix)
__global__ void cvt_wt_kernel(const float* __restrict__ in, ushort* __restrict__ out,
                              int nmat, int ncol) {
    int idx = blockIdx.x * blockDim.x + threadIdx.x;
    int total = nmat * 256 * ncol;
    if (idx >= total) return;
    int k = idx & 255;
    int t = idx >> 8;
    int n = t % ncol;
    int m = t / ncol;
    out[idx] = f2b(in[(size_t)m * 256 * ncol + (size_t)k * ncol + n]);
}

// ---------------- gather-mean: one wave per node, 4 neighbors in flight ----------------
// 4 groups of 16 lanes; group g walks neighbor i+g; each lane covers 16 cols (2x 16B loads).
__global__ __launch_bounds__(256) void gather_kernel(const ushort* __restrict__ h,
                                                     const int* __restrict__ csr_src,
                                                     const int* __restrict__ row_ptr,
                                                     const float* __restrict__ invd,
                                                     ushort* __restrict__ agg, int n) {
    const int node = blockIdx.x * 4 + (threadIdx.x >> 6);
    const int lane = threadIdx.x & 63;
    if (node >= n) return;
    const int beg = row_ptr[node];
    const int end = row_ptr[node + 1];
    const int g = lane >> 4;    // 0..3
    const int l16 = lane & 15;  // lane in group; cols l16*16 .. l16*16+15

    float a[16];
    #pragma unroll
    for (int j = 0; j < 16; ++j) a[j] = 0.f;

    int i = beg;
    for (; i + 3 < end; i += 4) {
        const int s = csr_src[i + g];
        const ushort* row = h + (size_t)s * D + l16 * 16;
        const u16x8 v0 = *reinterpret_cast<const u16x8*>(row);
        const u16x8 v1 = *reinterpret_cast<const u16x8*>(row + 8);
        #pragma unroll
        for (int j = 0; j < 8; ++j) { a[j] += b2f(v0[j]); a[8 + j] += b2f(v1[j]); }
    }
    if (i + g < end) {
        const int s = csr_src[i + g];
        const ushort* row = h + (size_t)s * D + l16 * 16;
        const u16x8 v0 = *reinterpret_cast<const u16x8*>(row);
        const u16x8 v1 = *reinterpret_cast<const u16x8*>(row + 8);
        #pragma unroll
        for (int j = 0; j < 8; ++j) { a[j] += b2f(v0[j]); a[8 + j] += b2f(v1[j]); }
    }
    // reduce across the 4 groups (same l16 -> same columns)
    #pragma unroll
    for (int j = 0; j < 16; ++j) {
        a[j] += __shfl_xor(a[j], 16);
        a[j] += __shfl_xor(a[j], 32);
    }
    if (g == 0) {
        const float sc = invd[node];
        u16x8 o0, o1;
        #pragma unroll
        for (int j = 0; j < 8; ++j) { o0[j] = f2b(a[j] * sc); o1[j] = f2b(a[8 + j] * sc); }
        ushort* w = agg + (size_t)node * D + l16 * 16;
        *reinterpret_cast<u16x8*>(w) = o0;
        *reinterpret_cast<u16x8*>(w + 8) = o1;
    }
}

// ---------------- bf16 MFMA GEMM, 128 rows x 256 cols per block, 512 threads ----------------
// out[n][j] = epi( bias[j] + sum_k A0[n][k]*B0T[j][k] (+ A1*B1T if DUAL) ), ncol == 256.
// A staged ONCE per k-step for all 256 output cols. 8 waves = 2 row-halves x 4 col-quarters.
template <bool DUAL, bool RELU, bool OUTBF>
__global__ __launch_bounds__(512) void mgemm256_kernel(
    const ushort* __restrict__ A0, const ushort* __restrict__ A1,
    const ushort* __restrict__ B0T, const ushort* __restrict__ B1T,
    const float* __restrict__ bias, void* __restrict__ out, int N)
{
    __shared__ ushort As[128][40];
    __shared__ ushort Bs[256][40];

    const int tid = threadIdx.x;
    const int wave = tid >> 6;   // 0..7
    const int lane = tid & 63;
    const int wm = wave >> 2;    // 0..1
    const int wn = wave & 3;     // 0..3
    const int l15 = lane & 15;
    const int l4 = lane >> 4;
    const int r0 = blockIdx.x * 128;

    const f32x4 zero = {0.f, 0.f, 0.f, 0.f};
    f32x4 acc[4][4];
    #pragma unroll
    for (int i = 0; i < 4; ++i)
        #pragma unroll
        for (int j = 0; j < 4; ++j) acc[i][j] = zero;

    // staging indices
    const int arr = tid >> 2;            // 0..127
    const int ach = (tid & 3) * 8;       // 0,8,16,24
    const int agrow = min(r0 + arr, N - 1);

    const int NT = DUAL ? 16 : 8;
    for (int kt = 0; kt < NT; ++kt) {
        const bool second = DUAL && (kt >= 8);
        const ushort* A = second ? A1 : A0;
        const ushort* BT = second ? B1T : B0T;
        const int kb = (second ? (kt - 8) : kt) * 32;

        *reinterpret_cast<float4*>(&As[arr][ach]) =
            *reinterpret_cast<const float4*>(A + (size_t)agrow * 256 + kb + ach);
        #pragma unroll
        for (int it = 0; it < 2; ++it) {
            const int idx = it * 512 + tid;
            const int br = idx >> 2;         // 0..255
            const int ch = (idx & 3) * 8;
            *reinterpret_cast<float4*>(&Bs[br][ch]) =
                *reinterpret_cast<const float4*>(BT + (size_t)br * 256 + kb + ch);
        }
        __syncthreads();

        bf16x8 af[4], bfr[4];
        #pragma unroll
        for (int i = 0; i < 4; ++i)
            af[i] = *reinterpret_cast<const bf16x8*>(&As[wm * 64 + 16 * i + l15][l4 * 8]);
        #pragma unroll
        for (int j = 0; j < 4; ++j)
            bfr[j] = *reinterpret_cast<const bf16x8*>(&Bs[wn * 64 + 16 * j + l15][l4 * 8]);
        #pragma unroll
        for (int i = 0; i < 4; ++i)
            #pragma unroll
            for (int j = 0; j < 4; ++j)
                acc[i][j] = __builtin_amdgcn_mfma_f32_16x16x32_bf16(af[i], bfr[j], acc[i][j], 0, 0, 0);
        __syncthreads();
    }

    const int rbase = r0 + wm * 64;
    const int cbase = wn * 64;
    #pragma unroll
    for (int i = 0; i < 4; ++i) {
        #pragma unroll
        for (int r = 0; r < 4; ++r) {
            const int row = rbase + 16 * i + l4 * 4 + r;
            if (row < N) {
                #pragma unroll
                for (int j = 0; j < 4; ++j) {
                    const int col = cbase + 16 * j + l15;
                    float v = acc[i][j][r] + bias[col];
                    if (RELU) v = fmaxf(v, 0.f);
                    if (OUTBF)
                        ((ushort*)out)[(size_t)row * 256 + col] = f2b(v);
                    else
                        ((float*)out)[(size_t)row * 256 + col] = v;
                }
            }
        }
    }
}

// ---------------- bf16 MFMA GEMM 128x128 (for ncol=128 final layer) ----------------
template <bool RELU, bool OUTBF>
__global__ __launch_bounds__(256) void mgemm128_kernel(
    const ushort* __restrict__ A0, const ushort* __restrict__ B0T,
    const float* __restrict__ bias, void* __restrict__ out, int N)
{
    __shared__ ushort As[128][40];
    __shared__ ushort Bs[128][40];

    const int tid = threadIdx.x;
    const int wave = tid >> 6;
    const int lane = tid & 63;
    const int wm = wave >> 1;
    const int wn = wave & 1;
    const int l15 = lane & 15;
    const int l4 = lane >> 4;
    const int r0 = blockIdx.x * 128;

    const f32x4 zero = {0.f, 0.f, 0.f, 0.f};
    f32x4 acc[4][4];
    #pragma unroll
    for (int i = 0; i < 4; ++i)
        #pragma unroll
        for (int j = 0; j < 4; ++j) acc[i][j] = zero;

    for (int kt = 0; kt < 8; ++kt) {
        const int kb = kt * 32;
        #pragma unroll
        for (int it = 0; it < 2; ++it) {
            const int idx = it * 256 + tid;
            const int rr = idx >> 2;
            const int ch = (idx & 3) * 8;
            const int grow = min(r0 + rr, N - 1);
            *reinterpret_cast<float4*>(&As[rr][ch]) =
                *reinterpret_cast<const float4*>(A0 + (size_t)grow * 256 + kb + ch);
            *reinterpret_cast<float4*>(&Bs[rr][ch]) =
                *reinterpret_cast<const float4*>(B0T + (size_t)rr * 256 + kb + ch);
        }
        __syncthreads();

        bf16x8 af[4], bfr[4];
        #pragma unroll
        for (int i = 0; i < 4; ++i)
            af[i] = *reinterpret_cast<const bf16x8*>(&As[wm * 64 + 16 * i + l15][l4 * 8]);
        #pragma unroll
        for (int j = 0; j < 4; ++j)
            bfr[j] = *reinterpret_cast<const bf16x8*>(&Bs[wn * 64 + 16 * j + l15][l4 * 8]);
        #pragma unroll
        for (int i = 0; i < 4; ++i)
            #pragma unroll
            for (int j = 0; j < 4; ++j)
                acc[i][j] = __builtin_amdgcn_mfma_f32_16x16x32_bf16(af[i], bfr[j], acc[i][j], 0, 0, 0);
        __syncthreads();
    }

    const int rbase = r0 + wm * 64;
    const int cbase = wn * 64;
    #pragma unroll
    for (int i = 0; i < 4; ++i) {
        #pragma unroll
        for (int r = 0; r < 4; ++r) {
            const int row = rbase + 16 * i + l4 * 4 + r;
            if (row < N) {
                #pragma unroll
                for (int j = 0; j < 4; ++j) {
                    const int col = cbase + 16 * j + l15;
                    float v = acc[i][j][r] + bias[col];
                    if (RELU) v = fmaxf(v, 0.f);
                    if (OUTBF)
                        ((ushort*)out)[(size_t)row * 128 + col] = f2b(v);
                    else
                        ((float*)out)[(size_t)row * 128 + col] = v;
                }
            }
        }
    }
}

// ---------------- log-softmax over 128 cols, one wave per row ----------------
__global__ void lsm_kernel(const float* __restrict__ in, float* __restrict__ out, int n) {
    const int wid = (int)(((long long)blockIdx.x * blockDim.x + threadIdx.x) >> 6);
    const int lane = threadIdx.x & 63;
    if (wid >= n) return;
    const float* row = in + (size_t)wid * DOUT;
    const float v0 = row[lane];
    const float v1 = row[lane + 64];
    float m = fmaxf(v0, v1);
    #pragma unroll
    for (int off = 32; off > 0; off >>= 1) m = fmaxf(m, __shfl_xor(m, off));
    float s = expf(v0 - m) + expf(v1 - m);
    #pragma unroll
    for (int off = 32; off > 0; off >>= 1) s += __shfl_xor(s, off);
    const float ls = m + logf(s);
    out[(size_t)wid * DOUT + lane] = v0 - ls;
    out[(size_t)wid * DOUT + lane + 64] = v1 - ls;
}

extern "C" void kernel_launch(void* const* d_in, const int* in_sizes, int n_in,
                              void* d_out, int out_size, void* d_ws, size_t ws_size,
                              hipStream_t stream) {
    const float* x  = (const float*)d_in[0];
    const int* ei   = (const int*)d_in[1];
    const float* wl = (const float*)d_in[2];
    const float* bl = (const float*)d_in[3];
    const float* wr = (const float*)d_in[4];
    const float* w1 = (const float*)d_in[5];
    const float* b1 = (const float*)d_in[6];
    const float* w2 = (const float*)d_in[7];
    const float* b2 = (const float*)d_in[8];
    const int* src = ei;
    const int* dst = ei + NE;

    // ---- workspace layout ----
    ushort* hx   = (ushort*)d_ws;                 // NN*D
    ushort* hA   = hx + (size_t)NN * D;           // NN*D
    ushort* hB   = hA + (size_t)NN * D;           // NN*D
    ushort* aggb = hB + (size_t)NN * D;           // NN*D
    ushort* wlT  = aggb + (size_t)NN * D;         // 3*256*256
    ushort* wrT  = wlT + 3 * 256 * 256;           // 3*256*256
    ushort* w1T  = wrT + 3 * 256 * 256;           // 256*256
    ushort* w2T  = w1T + 256 * 256;               // 128*256
    float* mp2o  = (float*)(w2T + 128 * 256);     // NN*DOUT
    float* invd  = mp2o + (size_t)NN * DOUT;      // NN
    int* degi    = (int*)(invd + NN);             // NN
    int* row_ptr = degi + NN;                     // NN+1
    int* cursor  = row_ptr + NN + 1;              // NN
    int* csr_src = cursor + NN;                   // NE
    int* blk     = csr_src + NE;                  // 256
    float* outf  = (float*)d_out;

    const int NB = (NN + 256) / 256;

    // ---- CSR build ----
    hipMemsetAsync(degi, 0, NN * sizeof(int), stream);
    hipMemsetAsync(cursor, 0, NN * sizeof(int), stream);
    deg_kernel<<<(NE + 255) / 256, 256, 0, stream>>>(dst, degi, NE);
    invd_kernel<<<(NN + 255) / 256, 256, 0, stream>>>(degi, invd, NN);
    scanA_kernel<<<NB, 256, 0, stream>>>(degi, blk, NN);
    scanB_kernel<<<1, 256, 0, stream>>>(blk, NB);
    scanC_kernel<<<NB, 256, 0, stream>>>(degi, blk, row_ptr, NN);
    fill_kernel<<<(NE + 255) / 256, 256, 0, stream>>>(src, dst, row_ptr, cursor, csr_src, NE);

    // ---- converts ----
    cvt_bf16_kernel<<<(NN * D / 4 + 255) / 256, 256, 0, stream>>>(x, hx, NN * D / 4);
    cvt_wt_kernel<<<(3 * 256 * 256 + 255) / 256, 256, 0, stream>>>(wl, wlT, 3, 256);
    cvt_wt_kernel<<<(3 * 256 * 256 + 255) / 256, 256, 0, stream>>>(wr, wrT, 3, 256);
    cvt_wt_kernel<<<(256 * 256 + 255) / 256, 256, 0, stream>>>(w1, w1T, 1, 256);
    cvt_wt_kernel<<<(128 * 256 + 255) / 256, 256, 0, stream>>>(w2, w2T, 1, 128);

    const int gpan = (NN + 127) / 128;  // 391 row panels

    const ushort* hin = hx;
    ushort* hout = hA;
    for (int l = 0; l < 3; ++l) {
        gather_kernel<<<(NN + 3) / 4, 256, 0, stream>>>(hin, csr_src, row_ptr, invd, aggb, NN);
        mgemm256_kernel<true, true, true><<<gpan, 512, 0, stream>>>(
            aggb, hin, wlT + (size_t)l * 256 * 256, wrT + (size_t)l * 256 * 256,
            bl + (size_t)l * 256, hout, NN);
        hin = hout;
        hout = (hout == hA) ? hB : hA;
    }
    // hin == hA, hout == hB
    mgemm256_kernel<false, false, true><<<gpan, 512, 0, stream>>>(
        hin, nullptr, w1T, nullptr, b1, hB, NN);
    mgemm128_kernel<false, false><<<gpan, 256, 0, stream>>>(
        hB, w2T, b2, mp2o, NN);
    lsm_kernel<<<((long long)NN * 64 + 255) / 256, 256, 0, stream>>>(mp2o, outf, NN);
}

// Round 6
// 413.486 us; speedup vs baseline: 21.1163x; 1.0207x over previous
//
#include <hip/hip_runtime.h>

#define NN 50000
#define NE 800000
#define D 256
#define DOUT 128

typedef __attribute__((ext_vector_type(8))) short bf16x8;
typedef __attribute__((ext_vector_type(8))) ushort u16x8;
typedef __attribute__((ext_vector_type(4))) float f32x4;

__device__ __forceinline__ ushort f2b(float f) {
    union { float f; unsigned u; } v; v.f = f;
    unsigned u = v.u + 0x7fffu + ((v.u >> 16) & 1u);
    return (ushort)(u >> 16);
}
__device__ __forceinline__ float b2f(ushort h) {
    union { unsigned u; float f; } v; v.u = ((unsigned)h) << 16;
    return v.f;
}
__device__ __forceinline__ float blo(unsigned u) {
    union { unsigned u; float f; } v; v.u = u << 16;
    return v.f;
}
__device__ __forceinline__ float bhi(unsigned u) {
    union { unsigned u; float f; } v; v.u = u & 0xffff0000u;
    return v.f;
}

// ---------------- CSR build ----------------
__global__ void deg_kernel(const int* __restrict__ dst, int* __restrict__ deg, int E) {
    int e = blockIdx.x * blockDim.x + threadIdx.x;
    if (e < E) atomicAdd(&deg[dst[e]], 1);
}

__global__ void invd_kernel(const int* __restrict__ deg, float* __restrict__ invd, int n) {
    int i = blockIdx.x * blockDim.x + threadIdx.x;
    if (i < n) invd[i] = 1.0f / fmaxf((float)deg[i], 1.0f);
}

__global__ __launch_bounds__(256) void scanA_kernel(const int* __restrict__ deg,
                                                    int* __restrict__ blk, int n) {
    __shared__ int red[4];
    const int i = blockIdx.x * 256 + threadIdx.x;
    int v = (i < n) ? deg[i] : 0;
    #pragma unroll
    for (int off = 32; off > 0; off >>= 1) v += __shfl_xor(v, off);
    if ((threadIdx.x & 63) == 0) red[threadIdx.x >> 6] = v;
    __syncthreads();
    if (threadIdx.x == 0) blk[blockIdx.x] = red[0] + red[1] + red[2] + red[3];
}

__global__ __launch_bounds__(256) void scanB_kernel(int* __restrict__ blk, int nb) {
    __shared__ int s[256];
    const int t = threadIdx.x;
    const int v = (t < nb) ? blk[t] : 0;
    s[t] = v;
    __syncthreads();
    for (int off = 1; off < 256; off <<= 1) {
        int u = (t >= off) ? s[t - off] : 0;
        __syncthreads();
        s[t] += u;
        __syncthreads();
    }
    if (t < nb) blk[t] = s[t] - v;  // exclusive
}

__global__ __launch_bounds__(256) void scanC_kernel(const int* __restrict__ deg,
                                                    const int* __restrict__ blk,
                                                    int* __restrict__ row_ptr, int n) {
    __shared__ int s[256];
    const int t = threadIdx.x;
    const int i = blockIdx.x * 256 + t;
    const int v = (i < n) ? deg[i] : 0;
    s[t] = v;
    __syncthreads();
    for (int off = 1; off < 256; off <<= 1) {
        int u = (t >= off) ? s[t - off] : 0;
        __syncthreads();
        s[t] += u;
        __syncthreads();
    }
    if (i <= n) row_ptr[i] = blk[blockIdx.x] + s[t] - v;
}

__global__ void fill_kernel(const int* __restrict__ src, const int* __restrict__ dst,
                            const int* __restrict__ row_ptr, int* __restrict__ cursor,
                            int* __restrict__ csr_src, int E) {
    int e = blockIdx.x * blockDim.x + threadIdx.x;
    if (e < E) {
        int d = dst[e];
        int pos = atomicAdd(&cursor[d], 1);
        csr_src[row_ptr[d] + pos] = src[e];
    }
}

// ---------------- converts ----------------
__global__ void cvt_bf16_kernel(const float* __restrict__ in, ushort* __restrict__ out, int n4) {
    int i = blockIdx.x * blockDim.x + threadIdx.x;
    if (i >= n4) return;
    const float4 v = *reinterpret_cast<const float4*>(in + (size_t)i * 4);
    ushort4 o;
    o.x = f2b(v.x); o.y = f2b(v.y); o.z = f2b(v.z); o.w = f2b(v.w);
    *reinterpret_cast<ushort4*>(out + (size_t)i * 4) = o;
}

// in: [nmat][256][ncol] f32  ->  out: [nmat][ncol][256] bf16 (transposed per matrix)
__global__ void cvt_wt_kernel(const float* __restrict__ in, ushort* __restrict__ out,
                              int nmat, int ncol) {
    int idx = blockIdx.x * blockDim.x + threadIdx.x;
    int total = nmat * 256 * ncol;
    if (idx >= total) return;
    int k = idx & 255;
    int t = idx >> 8;
    int n = t % ncol;
    int m = t / ncol;
    out[idx] = f2b(in[(size_t)m * 256 * ncol + (size_t)k * ncol + n]);
}

// ---------------- gather-mean: one wave per node, 8 neighbors / 4 loads per lane in flight ----
// 4 groups of 16 lanes; group g handles neighbors i+g and i+4+g; lane covers 16 cols (2x uint4).
__global__ __launch_bounds__(256) void gather_kernel(const ushort* __restrict__ h,
                                                     const int* __restrict__ csr_src,
                                                     const int* __restrict__ row_ptr,
                                                     const float* __restrict__ invd,
                                                     ushort* __restrict__ agg, int n) {
    const int node = blockIdx.x * 4 + (threadIdx.x >> 6);
    const int lane = threadIdx.x & 63;
    if (node >= n) return;
    const int beg = row_ptr[node];
    const int end = row_ptr[node + 1];
    const int g = lane >> 4;    // 0..3
    const int l16 = lane & 15;  // cols l16*16 .. l16*16+15

    float a[16];
    #pragma unroll
    for (int j = 0; j < 16; ++j) a[j] = 0.f;

    int i = beg;
    for (; i + 7 < end; i += 8) {
        const int s0 = csr_src[i + g];
        const int s1 = csr_src[i + 4 + g];
        const uint4* r0 = reinterpret_cast<const uint4*>(h + (size_t)s0 * D + l16 * 16);
        const uint4* r1 = reinterpret_cast<const uint4*>(h + (size_t)s1 * D + l16 * 16);
        const uint4 v00 = r0[0], v01 = r0[1];
        const uint4 v10 = r1[0], v11 = r1[1];
        const unsigned w0[8] = {v00.x, v00.y, v00.z, v00.w, v01.x, v01.y, v01.z, v01.w};
        const unsigned w1[8] = {v10.x, v10.y, v10.z, v10.w, v11.x, v11.y, v11.z, v11.w};
        #pragma unroll
        for (int j = 0; j < 8; ++j) {
            a[2 * j]     += blo(w0[j]) + blo(w1[j]);
            a[2 * j + 1] += bhi(w0[j]) + bhi(w1[j]);
        }
    }
    #pragma unroll
    for (int t = 0; t < 2; ++t) {
        const int idx = i + 4 * t + g;
        if (idx < end) {
            const int s = csr_src[idx];
            const uint4* r = reinterpret_cast<const uint4*>(h + (size_t)s * D + l16 * 16);
            const uint4 v0 = r[0], v1 = r[1];
            const unsigned w[8] = {v0.x, v0.y, v0.z, v0.w, v1.x, v1.y, v1.z, v1.w};
            #pragma unroll
            for (int j = 0; j < 8; ++j) {
                a[2 * j]     += blo(w[j]);
                a[2 * j + 1] += bhi(w[j]);
            }
        }
    }
    // reduce across the 4 groups (same l16 -> same columns)
    #pragma unroll
    for (int j = 0; j < 16; ++j) {
        a[j] += __shfl_xor(a[j], 16);
        a[j] += __shfl_xor(a[j], 32);
    }
    if (g == 0) {
        const float sc = invd[node];
        u16x8 o0, o1;
        #pragma unroll
        for (int j = 0; j < 8; ++j) { o0[j] = f2b(a[2 * j] * sc); o1[j] = f2b(a[2 * j + 1] * sc); }
        // note: o0/o1 hold interleaved (lo,hi) pairs == natural ushort order
        ushort* w = agg + (size_t)node * D + l16 * 16;
        ushort tmp[16];
        #pragma unroll
        for (int j = 0; j < 8; ++j) { tmp[2 * j] = o0[j]; tmp[2 * j + 1] = o1[j]; }
        *reinterpret_cast<u16x8*>(w)     = *reinterpret_cast<u16x8*>(&tmp[0]);
        *reinterpret_cast<u16x8*>(w + 8) = *reinterpret_cast<u16x8*>(&tmp[8]);
    }
}

// ---------------- bf16 MFMA GEMM, 128 rows x 256 cols per block, 512 threads ----------------
template <bool DUAL, bool RELU, bool OUTBF>
__global__ __launch_bounds__(512) void mgemm256_kernel(
    const ushort* __restrict__ A0, const ushort* __restrict__ A1,
    const ushort* __restrict__ B0T, const ushort* __restrict__ B1T,
    const float* __restrict__ bias, void* __restrict__ out, int N)
{
    __shared__ ushort As[128][40];
    __shared__ ushort Bs[256][40];

    const int tid = threadIdx.x;
    const int wave = tid >> 6;
    const int lane = tid & 63;
    const int wm = wave >> 2;
    const int wn = wave & 3;
    const int l15 = lane & 15;
    const int l4 = lane >> 4;
    const int r0 = blockIdx.x * 128;

    const f32x4 zero = {0.f, 0.f, 0.f, 0.f};
    f32x4 acc[4][4];
    #pragma unroll
    for (int i = 0; i < 4; ++i)
        #pragma unroll
        for (int j = 0; j < 4; ++j) acc[i][j] = zero;

    const int arr = tid >> 2;
    const int ach = (tid & 3) * 8;
    const int agrow = min(r0 + arr, N - 1);

    const int NT = DUAL ? 16 : 8;
    for (int kt = 0; kt < NT; ++kt) {
        const bool second = DUAL && (kt >= 8);
        const ushort* A = second ? A1 : A0;
        const ushort* BT = second ? B1T : B0T;
        const int kb = (second ? (kt - 8) : kt) * 32;

        *reinterpret_cast<float4*>(&As[arr][ach]) =
            *reinterpret_cast<const float4*>(A + (size_t)agrow * 256 + kb + ach);
        #pragma unroll
        for (int it = 0; it < 2; ++it) {
            const int idx = it * 512 + tid;
            const int br = idx >> 2;
            const int ch = (idx & 3) * 8;
            *reinterpret_cast<float4*>(&Bs[br][ch]) =
                *reinterpret_cast<const float4*>(BT + (size_t)br * 256 + kb + ch);
        }
        __syncthreads();

        bf16x8 af[4], bfr[4];
        #pragma unroll
        for (int i = 0; i < 4; ++i)
            af[i] = *reinterpret_cast<const bf16x8*>(&As[wm * 64 + 16 * i + l15][l4 * 8]);
        #pragma unroll
        for (int j = 0; j < 4; ++j)
            bfr[j] = *reinterpret_cast<const bf16x8*>(&Bs[wn * 64 + 16 * j + l15][l4 * 8]);
        #pragma unroll
        for (int i = 0; i < 4; ++i)
            #pragma unroll
            for (int j = 0; j < 4; ++j)
                acc[i][j] = __builtin_amdgcn_mfma_f32_16x16x32_bf16(af[i], bfr[j], acc[i][j], 0, 0, 0);
        __syncthreads();
    }

    const int rbase = r0 + wm * 64;
    const int cbase = wn * 64;
    #pragma unroll
    for (int i = 0; i < 4; ++i) {
        #pragma unroll
        for (int r = 0; r < 4; ++r) {
            const int row = rbase + 16 * i + l4 * 4 + r;
            if (row < N) {
                #pragma unroll
                for (int j = 0; j < 4; ++j) {
                    const int col = cbase + 16 * j + l15;
                    float v = acc[i][j][r] + bias[col];
                    if (RELU) v = fmaxf(v, 0.f);
                    if (OUTBF)
                        ((ushort*)out)[(size_t)row * 256 + col] = f2b(v);
                    else
                        ((float*)out)[(size_t)row * 256 + col] = v;
                }
            }
        }
    }
}

// ---------------- final GEMM (128 cols) with fused log-softmax ----------------
// 4 waves: wm=row-half, wn=col-half. Each 16-lane group owns full 64-col half of one row
// per (i,r), so softmax = 4-reg max/sum + 16-lane shfl reduce + LDS exchange across wn.
__global__ __launch_bounds__(256) void mgemm128sm_kernel(
    const ushort* __restrict__ A0, const ushort* __restrict__ B0T,
    const float* __restrict__ bias, float* __restrict__ out, int N)
{
    __shared__ ushort As[128][40];
    __shared__ ushort Bs[128][40];
    __shared__ float msh[2][128];
    __shared__ float ssh[2][128];

    const int tid = threadIdx.x;
    const int wave = tid >> 6;
    const int lane = tid & 63;
    const int wm = wave >> 1;
    const int wn = wave & 1;
    const int l15 = lane & 15;
    const int l4 = lane >> 4;
    const int r0 = blockIdx.x * 128;

    const f32x4 zero = {0.f, 0.f, 0.f, 0.f};
    f32x4 acc[4][4];
    #pragma unroll
    for (int i = 0; i < 4; ++i)
        #pragma unroll
        for (int j = 0; j < 4; ++j) acc[i][j] = zero;

    for (int kt = 0; kt < 8; ++kt) {
        const int kb = kt * 32;
        #pragma unroll
        for (int it = 0; it < 2; ++it) {
            const int idx = it * 256 + tid;
            const int rr = idx >> 2;
            const int ch = (idx & 3) * 8;
            const int grow = min(r0 + rr, N - 1);
            *reinterpret_cast<float4*>(&As[rr][ch]) =
                *reinterpret_cast<const float4*>(A0 + (size_t)grow * 256 + kb + ch);
            *reinterpret_cast<float4*>(&Bs[rr][ch]) =
                *reinterpret_cast<const float4*>(B0T + (size_t)rr * 256 + kb + ch);
        }
        __syncthreads();

        bf16x8 af[4], bfr[4];
        #pragma unroll
        for (int i = 0; i < 4; ++i)
            af[i] = *reinterpret_cast<const bf16x8*>(&As[wm * 64 + 16 * i + l15][l4 * 8]);
        #pragma unroll
        for (int j = 0; j < 4; ++j)
            bfr[j] = *reinterpret_cast<const bf16x8*>(&Bs[wn * 64 + 16 * j + l15][l4 * 8]);
        #pragma unroll
        for (int i = 0; i < 4; ++i)
            #pragma unroll
            for (int j = 0; j < 4; ++j)
                acc[i][j] = __builtin_amdgcn_mfma_f32_16x16x32_bf16(af[i], bfr[j], acc[i][j], 0, 0, 0);
        __syncthreads();
    }

    const int rbase = r0 + wm * 64;
    const int cbase = wn * 64;
    float bb[4];
    #pragma unroll
    for (int j = 0; j < 4; ++j) bb[j] = bias[cbase + 16 * j + l15];

    // phase 1: per-(i,r) half-row max & exp-sum
    #pragma unroll
    for (int i = 0; i < 4; ++i) {
        #pragma unroll
        for (int r = 0; r < 4; ++r) {
            float v0 = acc[i][0][r] + bb[0];
            float v1 = acc[i][1][r] + bb[1];
            float v2 = acc[i][2][r] + bb[2];
            float v3 = acc[i][3][r] + bb[3];
            float m = fmaxf(fmaxf(v0, v1), fmaxf(v2, v3));
            #pragma unroll
            for (int off = 8; off > 0; off >>= 1) m = fmaxf(m, __shfl_xor(m, off));
            float s = expf(v0 - m) + expf(v1 - m) + expf(v2 - m) + expf(v3 - m);
            #pragma unroll
            for (int off = 8; off > 0; off >>= 1) s += __shfl_xor(s, off);
            if (l15 == 0) {
                const int lr = wm * 64 + 16 * i + l4 * 4 + r;
                msh[wn][lr] = m;
                ssh[wn][lr] = s;
            }
        }
    }
    __syncthreads();

    // phase 2: combine halves, write v - lse
    #pragma unroll
    for (int i = 0; i < 4; ++i) {
        #pragma unroll
        for (int r = 0; r < 4; ++r) {
            const int lr = wm * 64 + 16 * i + l4 * 4 + r;
            const float m0 = msh[0][lr], m1 = msh[1][lr];
            const float s0 = ssh[0][lr], s1 = ssh[1][lr];
            const float M = fmaxf(m0, m1);
            const float ls = M + logf(s0 * expf(m0 - M) + s1 * expf(m1 - M));
            const int row = r0 + lr;
            if (row < N) {
                #pragma unroll
                for (int j = 0; j < 4; ++j)
                    out[(size_t)row * DOUT + cbase + 16 * j + l15] = acc[i][j][r] + bb[j] - ls;
            }
        }
    }
}

extern "C" void kernel_launch(void* const* d_in, const int* in_sizes, int n_in,
                              void* d_out, int out_size, void* d_ws, size_t ws_size,
                              hipStream_t stream) {
    const float* x  = (const float*)d_in[0];
    const int* ei   = (const int*)d_in[1];
    const float* wl = (const float*)d_in[2];
    const float* bl = (const float*)d_in[3];
    const float* wr = (const float*)d_in[4];
    const float* w1 = (const float*)d_in[5];
    const float* b1 = (const float*)d_in[6];
    const float* w2 = (const float*)d_in[7];
    const float* b2 = (const float*)d_in[8];
    const int* src = ei;
    const int* dst = ei + NE;

    // ---- workspace layout ----
    ushort* hx   = (ushort*)d_ws;                 // NN*D
    ushort* hA   = hx + (size_t)NN * D;           // NN*D
    ushort* hB   = hA + (size_t)NN * D;           // NN*D
    ushort* aggb = hB + (size_t)NN * D;           // NN*D
    ushort* wlT  = aggb + (size_t)NN * D;         // 3*256*256
    ushort* wrT  = wlT + 3 * 256 * 256;           // 3*256*256
    ushort* w1T  = wrT + 3 * 256 * 256;           // 256*256
    ushort* w2T  = w1T + 256 * 256;               // 128*256
    float* invd  = (float*)(w2T + 128 * 256);     // NN
    int* degi    = (int*)(invd + NN);             // NN
    int* row_ptr = degi + NN;                     // NN+1
    int* cursor  = row_ptr + NN + 1;              // NN
    int* csr_src = cursor + NN;                   // NE
    int* blk     = csr_src + NE;                  // 256
    float* outf  = (float*)d_out;

    const int NB = (NN + 256) / 256;

    // ---- CSR build ----
    hipMemsetAsync(degi, 0, NN * sizeof(int), stream);
    hipMemsetAsync(cursor, 0, NN * sizeof(int), stream);
    deg_kernel<<<(NE + 255) / 256, 256, 0, stream>>>(dst, degi, NE);
    invd_kernel<<<(NN + 255) / 256, 256, 0, stream>>>(degi, invd, NN);
    scanA_kernel<<<NB, 256, 0, stream>>>(degi, blk, NN);
    scanB_kernel<<<1, 256, 0, stream>>>(blk, NB);
    scanC_kernel<<<NB, 256, 0, stream>>>(degi, blk, row_ptr, NN);
    fill_kernel<<<(NE + 255) / 256, 256, 0, stream>>>(src, dst, row_ptr, cursor, csr_src, NE);

    // ---- converts ----
    cvt_bf16_kernel<<<(NN * D / 4 + 255) / 256, 256, 0, stream>>>(x, hx, NN * D / 4);
    cvt_wt_kernel<<<(3 * 256 * 256 + 255) / 256, 256, 0, stream>>>(wl, wlT, 3, 256);
    cvt_wt_kernel<<<(3 * 256 * 256 + 255) / 256, 256, 0, stream>>>(wr, wrT, 3, 256);
    cvt_wt_kernel<<<(256 * 256 + 255) / 256, 256, 0, stream>>>(w1, w1T, 1, 256);
    cvt_wt_kernel<<<(128 * 256 + 255) / 256, 256, 0, stream>>>(w2, w2T, 1, 128);

    const int gpan = (NN + 127) / 128;

    const ushort* hin = hx;
    ushort* hout = hA;
    for (int l = 0; l < 3; ++l) {
        gather_kernel<<<(NN + 3) / 4, 256, 0, stream>>>(hin, csr_src, row_ptr, invd, aggb, NN);
        mgemm256_kernel<true, true, true><<<gpan, 512, 0, stream>>>(
            aggb, hin, wlT + (size_t)l * 256 * 256, wrT + (size_t)l * 256 * 256,
            bl + (size_t)l * 256, hout, NN);
        hin = hout;
        hout = (hout == hA) ? hB : hA;
    }
    // hin == hA, hout == hB
    mgemm256_kernel<false, false, true><<<gpan, 512, 0, stream>>>(
        hin, nullptr, w1T, nullptr, b1, hB, NN);
    mgemm128sm_kernel<<<gpan, 256, 0, stream>>>(hB, w2T, b2, outf, NN);
}

// Round 7
// 391.564 us; speedup vs baseline: 22.2985x; 1.0560x over previous
//
#include <hip/hip_runtime.h>

#define NN 50000
#define NE 800000
#define D 256
#define DOUT 128

typedef __attribute__((ext_vector_type(8))) short bf16x8;
typedef __attribute__((ext_vector_type(8))) ushort u16x8;
typedef __attribute__((ext_vector_type(4))) float f32x4;
typedef __attribute__((ext_vector_type(2))) float f32x2;

__device__ __forceinline__ ushort f2b(float f) {
    union { float f; unsigned u; } v; v.f = f;
    unsigned u = v.u + 0x7fffu + ((v.u >> 16) & 1u);
    return (ushort)(u >> 16);
}
__device__ __forceinline__ float b2f(ushort h) {
    union { unsigned u; float f; } v; v.u = ((unsigned)h) << 16;
    return v.f;
}
__device__ __forceinline__ unsigned char f2fp8(float f) {
    return (unsigned char)(__builtin_amdgcn_cvt_pk_fp8_f32(f, 0.f, 0, 0) & 0xff);
}

// ---------------- CSR build ----------------
__global__ void deg_kernel(const int* __restrict__ dst, int* __restrict__ deg, int E) {
    int e = blockIdx.x * blockDim.x + threadIdx.x;
    if (e < E) atomicAdd(&deg[dst[e]], 1);
}

__global__ void invd_kernel(const int* __restrict__ deg, float* __restrict__ invd, int n) {
    int i = blockIdx.x * blockDim.x + threadIdx.x;
    if (i < n) invd[i] = 1.0f / fmaxf((float)deg[i], 1.0f);
}

__global__ __launch_bounds__(256) void scanA_kernel(const int* __restrict__ deg,
                                                    int* __restrict__ blk, int n) {
    __shared__ int red[4];
    const int i = blockIdx.x * 256 + threadIdx.x;
    int v = (i < n) ? deg[i] : 0;
    #pragma unroll
    for (int off = 32; off > 0; off >>= 1) v += __shfl_xor(v, off);
    if ((threadIdx.x & 63) == 0) red[threadIdx.x >> 6] = v;
    __syncthreads();
    if (threadIdx.x == 0) blk[blockIdx.x] = red[0] + red[1] + red[2] + red[3];
}

__global__ __launch_bounds__(256) void scanB_kernel(int* __restrict__ blk, int nb) {
    __shared__ int s[256];
    const int t = threadIdx.x;
    const int v = (t < nb) ? blk[t] : 0;
    s[t] = v;
    __syncthreads();
    for (int off = 1; off < 256; off <<= 1) {
        int u = (t >= off) ? s[t - off] : 0;
        __syncthreads();
        s[t] += u;
        __syncthreads();
    }
    if (t < nb) blk[t] = s[t] - v;  // exclusive
}

__global__ __launch_bounds__(256) void scanC_kernel(const int* __restrict__ deg,
                                                    const int* __restrict__ blk,
                                                    int* __restrict__ row_ptr, int n) {
    __shared__ int s[256];
    const int t = threadIdx.x;
    const int i = blockIdx.x * 256 + t;
    const int v = (i < n) ? deg[i] : 0;
    s[t] = v;
    __syncthreads();
    for (int off = 1; off < 256; off <<= 1) {
        int u = (t >= off) ? s[t - off] : 0;
        __syncthreads();
        s[t] += u;
        __syncthreads();
    }
    if (i <= n) row_ptr[i] = blk[blockIdx.x] + s[t] - v;
}

__global__ void fill_kernel(const int* __restrict__ src, const int* __restrict__ dst,
                            const int* __restrict__ row_ptr, int* __restrict__ cursor,
                            int* __restrict__ csr_src, int E) {
    int e = blockIdx.x * blockDim.x + threadIdx.x;
    if (e < E) {
        int d = dst[e];
        int pos = atomicAdd(&cursor[d], 1);
        csr_src[row_ptr[d] + pos] = src[e];
    }
}

// ---------------- converts ----------------
// x f32 -> bf16 AND fp8 shadow
__global__ void cvt_x_kernel(const float* __restrict__ in, ushort* __restrict__ outb,
                             unsigned* __restrict__ out8, int n4) {
    int i = blockIdx.x * blockDim.x + threadIdx.x;
    if (i >= n4) return;
    const float4 v = *reinterpret_cast<const float4*>(in + (size_t)i * 4);
    ushort4 o;
    o.x = f2b(v.x); o.y = f2b(v.y); o.z = f2b(v.z); o.w = f2b(v.w);
    *reinterpret_cast<ushort4*>(outb + (size_t)i * 4) = o;
    unsigned p = __builtin_amdgcn_cvt_pk_fp8_f32(v.x, v.y, 0, 0);
    p = __builtin_amdgcn_cvt_pk_fp8_f32(v.z, v.w, p, 1);
    out8[i] = p;
}

// in: [nmat][256][ncol] f32  ->  out: [nmat][ncol][256] bf16 (transposed per matrix)
__global__ void cvt_wt_kernel(const float* __restrict__ in, ushort* __restrict__ out,
                              int nmat, int ncol) {
    int idx = blockIdx.x * blockDim.x + threadIdx.x;
    int total = nmat * 256 * ncol;
    if (idx >= total) return;
    int k = idx & 255;
    int t = idx >> 8;
    int n = t % ncol;
    int m = t / ncol;
    out[idx] = f2b(in[(size_t)m * 256 * ncol + (size_t)k * ncol + n]);
}

// ---------------- gather-mean over fp8 rows: one wave per node, 16 neighbors in flight ------
// 4 groups of 16 lanes; group g handles neighbors i+g, i+4+g, i+8+g, i+12+g.
// Each lane reads one uint4 (16 fp8 = cols l16*16 .. +15) per row; HW cvt unpack.
__global__ __launch_bounds__(256) void gather_kernel(const unsigned char* __restrict__ h8,
                                                     const int* __restrict__ csr_src,
                                                     const int* __restrict__ row_ptr,
                                                     const float* __restrict__ invd,
                                                     ushort* __restrict__ agg, int n) {
    const int node = blockIdx.x * 4 + (threadIdx.x >> 6);
    const int lane = threadIdx.x & 63;
    if (node >= n) return;
    const int beg = row_ptr[node];
    const int end = row_ptr[node + 1];
    const int g = lane >> 4;    // 0..3
    const int l16 = lane & 15;  // cols l16*16 .. l16*16+15

    float a[16];
    #pragma unroll
    for (int j = 0; j < 16; ++j) a[j] = 0.f;

    int i = beg;
    for (; i + 15 < end; i += 16) {
        const int s0 = csr_src[i + g];
        const int s1 = csr_src[i + 4 + g];
        const int s2 = csr_src[i + 8 + g];
        const int s3 = csr_src[i + 12 + g];
        const uint4 v0 = *reinterpret_cast<const uint4*>(h8 + (size_t)s0 * D + l16 * 16);
        const uint4 v1 = *reinterpret_cast<const uint4*>(h8 + (size_t)s1 * D + l16 * 16);
        const uint4 v2 = *reinterpret_cast<const uint4*>(h8 + (size_t)s2 * D + l16 * 16);
        const uint4 v3 = *reinterpret_cast<const uint4*>(h8 + (size_t)s3 * D + l16 * 16);
        const unsigned w[16] = {v0.x, v0.y, v0.z, v0.w, v1.x, v1.y, v1.z, v1.w,
                                v2.x, v2.y, v2.z, v2.w, v3.x, v3.y, v3.z, v3.w};
        #pragma unroll
        for (int q = 0; q < 16; ++q) {
            const f32x2 lo = __builtin_amdgcn_cvt_pk_f32_fp8(w[q], 0);
            const f32x2 hi = __builtin_amdgcn_cvt_pk_f32_fp8(w[q], 1);
            const int b = (q & 3) * 4;
            a[b + 0] += lo.x; a[b + 1] += lo.y; a[b + 2] += hi.x; a[b + 3] += hi.y;
        }
    }
    #pragma unroll
    for (int t = 0; t < 4; ++t) {
        const int idx = i + 4 * t + g;
        if (idx < end) {
            const int s = csr_src[idx];
            const uint4 v = *reinterpret_cast<const uint4*>(h8 + (size_t)s * D + l16 * 16);
            const unsigned w[4] = {v.x, v.y, v.z, v.w};
            #pragma unroll
            for (int q = 0; q < 4; ++q) {
                const f32x2 lo = __builtin_amdgcn_cvt_pk_f32_fp8(w[q], 0);
                const f32x2 hi = __builtin_amdgcn_cvt_pk_f32_fp8(w[q], 1);
                a[4 * q + 0] += lo.x; a[4 * q + 1] += lo.y;
                a[4 * q + 2] += hi.x; a[4 * q + 3] += hi.y;
            }
        }
    }
    // reduce across the 4 groups (same l16 -> same columns)
    #pragma unroll
    for (int j = 0; j < 16; ++j) {
        a[j] += __shfl_xor(a[j], 16);
        a[j] += __shfl_xor(a[j], 32);
    }
    if (g == 0) {
        const float sc = invd[node];
        ushort tmp[16];
        #pragma unroll
        for (int j = 0; j < 16; ++j) tmp[j] = f2b(a[j] * sc);
        ushort* w = agg + (size_t)node * D + l16 * 16;
        *reinterpret_cast<u16x8*>(w)     = *reinterpret_cast<u16x8*>(&tmp[0]);
        *reinterpret_cast<u16x8*>(w + 8) = *reinterpret_cast<u16x8*>(&tmp[8]);
    }
}

// ---------------- bf16 MFMA GEMM, 128 rows x 256 cols per block, 512 threads ----------------
// OUT8: additionally write fp8 shadow copy (for next layer's gather).
template <bool DUAL, bool RELU, bool OUTBF, bool OUT8>
__global__ __launch_bounds__(512) void mgemm256_kernel(
    const ushort* __restrict__ A0, const ushort* __restrict__ A1,
    const ushort* __restrict__ B0T, const ushort* __restrict__ B1T,
    const float* __restrict__ bias, void* __restrict__ out,
    unsigned char* __restrict__ out8, int N)
{
    __shared__ ushort As[128][40];
    __shared__ ushort Bs[256][40];

    const int tid = threadIdx.x;
    const int wave = tid >> 6;
    const int lane = tid & 63;
    const int wm = wave >> 2;
    const int wn = wave & 3;
    const int l15 = lane & 15;
    const int l4 = lane >> 4;
    const int r0 = blockIdx.x * 128;

    const f32x4 zero = {0.f, 0.f, 0.f, 0.f};
    f32x4 acc[4][4];
    #pragma unroll
    for (int i = 0; i < 4; ++i)
        #pragma unroll
        for (int j = 0; j < 4; ++j) acc[i][j] = zero;

    const int arr = tid >> 2;
    const int ach = (tid & 3) * 8;
    const int agrow = min(r0 + arr, N - 1);

    const int NT = DUAL ? 16 : 8;
    for (int kt = 0; kt < NT; ++kt) {
        const bool second = DUAL && (kt >= 8);
        const ushort* A = second ? A1 : A0;
        const ushort* BT = second ? B1T : B0T;
        const int kb = (second ? (kt - 8) : kt) * 32;

        *reinterpret_cast<float4*>(&As[arr][ach]) =
            *reinterpret_cast<const float4*>(A + (size_t)agrow * 256 + kb + ach);
        #pragma unroll
        for (int it = 0; it < 2; ++it) {
            const int idx = it * 512 + tid;
            const int br = idx >> 2;
            const int ch = (idx & 3) * 8;
            *reinterpret_cast<float4*>(&Bs[br][ch]) =
                *reinterpret_cast<const float4*>(BT + (size_t)br * 256 + kb + ch);
        }
        __syncthreads();

        bf16x8 af[4], bfr[4];
        #pragma unroll
        for (int i = 0; i < 4; ++i)
            af[i] = *reinterpret_cast<const bf16x8*>(&As[wm * 64 + 16 * i + l15][l4 * 8]);
        #pragma unroll
        for (int j = 0; j < 4; ++j)
            bfr[j] = *reinterpret_cast<const bf16x8*>(&Bs[wn * 64 + 16 * j + l15][l4 * 8]);
        #pragma unroll
        for (int i = 0; i < 4; ++i)
            #pragma unroll
            for (int j = 0; j < 4; ++j)
                acc[i][j] = __builtin_amdgcn_mfma_f32_16x16x32_bf16(af[i], bfr[j], acc[i][j], 0, 0, 0);
        __syncthreads();
    }

    const int rbase = r0 + wm * 64;
    const int cbase = wn * 64;
    #pragma unroll
    for (int i = 0; i < 4; ++i) {
        #pragma unroll
        for (int r = 0; r < 4; ++r) {
            const int row = rbase + 16 * i + l4 * 4 + r;
            if (row < N) {
                #pragma unroll
                for (int j = 0; j < 4; ++j) {
                    const int col = cbase + 16 * j + l15;
                    float v = acc[i][j][r] + bias[col];
                    if (RELU) v = fmaxf(v, 0.f);
                    if (OUTBF)
                        ((ushort*)out)[(size_t)row * 256 + col] = f2b(v);
                    else
                        ((float*)out)[(size_t)row * 256 + col] = v;
                    if (OUT8)
                        out8[(size_t)row * 256 + col] = f2fp8(v);
                }
            }
        }
    }
}

// ---------------- final GEMM (128 cols) with fused log-softmax ----------------
__global__ __launch_bounds__(256) void mgemm128sm_kernel(
    const ushort* __restrict__ A0, const ushort* __restrict__ B0T,
    const float* __restrict__ bias, float* __restrict__ out, int N)
{
    __shared__ ushort As[128][40];
    __shared__ ushort Bs[128][40];
    __shared__ float msh[2][128];
    __shared__ float ssh[2][128];

    const int tid = threadIdx.x;
    const int wave = tid >> 6;
    const int lane = tid & 63;
    const int wm = wave >> 1;
    const int wn = wave & 1;
    const int l15 = lane & 15;
    const int l4 = lane >> 4;
    const int r0 = blockIdx.x * 128;

    const f32x4 zero = {0.f, 0.f, 0.f, 0.f};
    f32x4 acc[4][4];
    #pragma unroll
    for (int i = 0; i < 4; ++i)
        #pragma unroll
        for (int j = 0; j < 4; ++j) acc[i][j] = zero;

    for (int kt = 0; kt < 8; ++kt) {
        const int kb = kt * 32;
        #pragma unroll
        for (int it = 0; it < 2; ++it) {
            const int idx = it * 256 + tid;
            const int rr = idx >> 2;
            const int ch = (idx & 3) * 8;
            const int grow = min(r0 + rr, N - 1);
            *reinterpret_cast<float4*>(&As[rr][ch]) =
                *reinterpret_cast<const float4*>(A0 + (size_t)grow * 256 + kb + ch);
            *reinterpret_cast<float4*>(&Bs[rr][ch]) =
                *reinterpret_cast<const float4*>(B0T + (size_t)rr * 256 + kb + ch);
        }
        __syncthreads();

        bf16x8 af[4], bfr[4];
        #pragma unroll
        for (int i = 0; i < 4; ++i)
            af[i] = *reinterpret_cast<const bf16x8*>(&As[wm * 64 + 16 * i + l15][l4 * 8]);
        #pragma unroll
        for (int j = 0; j < 4; ++j)
            bfr[j] = *reinterpret_cast<const bf16x8*>(&Bs[wn * 64 + 16 * j + l15][l4 * 8]);
        #pragma unroll
        for (int i = 0; i < 4; ++i)
            #pragma unroll
            for (int j = 0; j < 4; ++j)
                acc[i][j] = __builtin_amdgcn_mfma_f32_16x16x32_bf16(af[i], bfr[j], acc[i][j], 0, 0, 0);
        __syncthreads();
    }

    const int cbase = wn * 64;
    float bb[4];
    #pragma unroll
    for (int j = 0; j < 4; ++j) bb[j] = bias[cbase + 16 * j + l15];

    #pragma unroll
    for (int i = 0; i < 4; ++i) {
        #pragma unroll
        for (int r = 0; r < 4; ++r) {
            float v0 = acc[i][0][r] + bb[0];
            float v1 = acc[i][1][r] + bb[1];
            float v2 = acc[i][2][r] + bb[2];
            float v3 = acc[i][3][r] + bb[3];
            float m = fmaxf(fmaxf(v0, v1), fmaxf(v2, v3));
            #pragma unroll
            for (int off = 8; off > 0; off >>= 1) m = fmaxf(m, __shfl_xor(m, off));
            float s = expf(v0 - m) + expf(v1 - m) + expf(v2 - m) + expf(v3 - m);
            #pragma unroll
            for (int off = 8; off > 0; off >>= 1) s += __shfl_xor(s, off);
            if (l15 == 0) {
                const int lr = wm * 64 + 16 * i + l4 * 4 + r;
                msh[wn][lr] = m;
                ssh[wn][lr] = s;
            }
        }
    }
    __syncthreads();

    #pragma unroll
    for (int i = 0; i < 4; ++i) {
        #pragma unroll
        for (int r = 0; r < 4; ++r) {
            const int lr = wm * 64 + 16 * i + l4 * 4 + r;
            const float m0 = msh[0][lr], m1 = msh[1][lr];
            const float s0 = ssh[0][lr], s1 = ssh[1][lr];
            const float M = fmaxf(m0, m1);
            const float ls = M + logf(s0 * expf(m0 - M) + s1 * expf(m1 - M));
            const int row = r0 + lr;
            if (row < N) {
                #pragma unroll
                for (int j = 0; j < 4; ++j)
                    out[(size_t)row * DOUT + cbase + 16 * j + l15] = acc[i][j][r] + bb[j] - ls;
            }
        }
    }
}

extern "C" void kernel_launch(void* const* d_in, const int* in_sizes, int n_in,
                              void* d_out, int out_size, void* d_ws, size_t ws_size,
                              hipStream_t stream) {
    const float* x  = (const float*)d_in[0];
    const int* ei   = (const int*)d_in[1];
    const float* wl = (const float*)d_in[2];
    const float* bl = (const float*)d_in[3];
    const float* wr = (const float*)d_in[4];
    const float* w1 = (const float*)d_in[5];
    const float* b1 = (const float*)d_in[6];
    const float* w2 = (const float*)d_in[7];
    const float* b2 = (const float*)d_in[8];
    const int* src = ei;
    const int* dst = ei + NE;

    // ---- workspace layout ----
    ushort* hx   = (ushort*)d_ws;                 // NN*D bf16
    ushort* hA   = hx + (size_t)NN * D;
    ushort* hB   = hA + (size_t)NN * D;
    ushort* aggb = hB + (size_t)NN * D;
    ushort* wlT  = aggb + (size_t)NN * D;         // 3*256*256
    ushort* wrT  = wlT + 3 * 256 * 256;
    ushort* w1T  = wrT + 3 * 256 * 256;
    ushort* w2T  = w1T + 256 * 256;               // 128*256
    unsigned char* h8x = (unsigned char*)(w2T + 128 * 256);  // NN*D fp8
    unsigned char* h8A = h8x + (size_t)NN * D;
    unsigned char* h8B = h8A + (size_t)NN * D;
    float* invd  = (float*)(h8B + (size_t)NN * D);
    int* degi    = (int*)(invd + NN);
    int* row_ptr = degi + NN;
    int* cursor  = row_ptr + NN + 1;
    int* csr_src = cursor + NN;
    int* blk     = csr_src + NE;
    float* outf  = (float*)d_out;

    const int NB = (NN + 256) / 256;

    // ---- CSR build ----
    hipMemsetAsync(degi, 0, NN * sizeof(int), stream);
    hipMemsetAsync(cursor, 0, NN * sizeof(int), stream);
    deg_kernel<<<(NE + 255) / 256, 256, 0, stream>>>(dst, degi, NE);
    invd_kernel<<<(NN + 255) / 256, 256, 0, stream>>>(degi, invd, NN);
    scanA_kernel<<<NB, 256, 0, stream>>>(degi, blk, NN);
    scanB_kernel<<<1, 256, 0, stream>>>(blk, NB);
    scanC_kernel<<<NB, 256, 0, stream>>>(degi, blk, row_ptr, NN);
    fill_kernel<<<(NE + 255) / 256, 256, 0, stream>>>(src, dst, row_ptr, cursor, csr_src, NE);

    // ---- converts ----
    cvt_x_kernel<<<(NN * D / 4 + 255) / 256, 256, 0, stream>>>(x, hx, (unsigned*)h8x, NN * D / 4);
    cvt_wt_kernel<<<(3 * 256 * 256 + 255) / 256, 256, 0, stream>>>(wl, wlT, 3, 256);
    cvt_wt_kernel<<<(3 * 256 * 256 + 255) / 256, 256, 0, stream>>>(wr, wrT, 3, 256);
    cvt_wt_kernel<<<(256 * 256 + 255) / 256, 256, 0, stream>>>(w1, w1T, 1, 256);
    cvt_wt_kernel<<<(128 * 256 + 255) / 256, 256, 0, stream>>>(w2, w2T, 1, 128);

    const int gpan = (NN + 127) / 128;
    const int gg = (NN + 3) / 4;

    // layer 0: gather(h8x) ; A1 = hx -> hA (+h8A)
    gather_kernel<<<gg, 256, 0, stream>>>(h8x, csr_src, row_ptr, invd, aggb, NN);
    mgemm256_kernel<true, true, true, true><<<gpan, 512, 0, stream>>>(
        aggb, hx, wlT, wrT, bl, hA, h8A, NN);
    // layer 1: gather(h8A) ; A1 = hA -> hB (+h8B)
    gather_kernel<<<gg, 256, 0, stream>>>(h8A, csr_src, row_ptr, invd, aggb, NN);
    mgemm256_kernel<true, true, true, true><<<gpan, 512, 0, stream>>>(
        aggb, hA, wlT + 256 * 256, wrT + 256 * 256, bl + 256, hB, h8B, NN);
    // layer 2: gather(h8B) ; A1 = hB -> hA (no fp8 needed)
    gather_kernel<<<gg, 256, 0, stream>>>(h8B, csr_src, row_ptr, invd, aggb, NN);
    mgemm256_kernel<true, true, true, false><<<gpan, 512, 0, stream>>>(
        aggb, hB, wlT + 2 * 256 * 256, wrT + 2 * 256 * 256, bl + 2 * 256, hA, nullptr, NN);
    // post-mp
    mgemm256_kernel<false, false, true, false><<<gpan, 512, 0, stream>>>(
        hA, nullptr, w1T, nullptr, b1, hB, nullptr, NN);
    mgemm128sm_kernel<<<gpan, 256, 0, stream>>>(hB, w2T, b2, outf, NN);
}

// Round 8
// 341.965 us; speedup vs baseline: 25.5327x; 1.1450x over previous
//
#include <hip/hip_runtime.h>

#define NN 50000
#define NE 800000
#define D 256
#define DOUT 128

// bucket sort params: 196 buckets of 256 nodes; 98 blocks of 8192 edges
#define NBUCK 196
#define EPB 8192
#define NBLK 98
#define NSCAN (NBUCK * NBLK)  // 19208

typedef __attribute__((ext_vector_type(8))) short bf16x8;
typedef __attribute__((ext_vector_type(8))) ushort u16x8;
typedef __attribute__((ext_vector_type(4))) float f32x4;
typedef __attribute__((ext_vector_type(2))) float f32x2;

__device__ __forceinline__ ushort f2b(float f) {
    union { float f; unsigned u; } v; v.f = f;
    unsigned u = v.u + 0x7fffu + ((v.u >> 16) & 1u);
    return (ushort)(u >> 16);
}
__device__ __forceinline__ unsigned char f2fp8(float f) {
    return (unsigned char)(__builtin_amdgcn_cvt_pk_fp8_f32(f, 0.f, 0, 0) & 0xff);
}

// ---------------- bucketed CSR build ----------------
__global__ __launch_bounds__(256) void bcount_kernel(const int* __restrict__ dst,
                                                     int* __restrict__ gcnt, int E) {
    __shared__ int hist[NBUCK];
    const int b = blockIdx.x;
    for (int i = threadIdx.x; i < NBUCK; i += 256) hist[i] = 0;
    __syncthreads();
    const int e0 = b * EPB;
    const int e1 = min(e0 + EPB, E);
    for (int e = e0 + threadIdx.x; e < e1; e += 256)
        atomicAdd(&hist[dst[e] >> 8], 1);
    __syncthreads();
    for (int q = threadIdx.x; q < NBUCK; q += 256)
        gcnt[q * NBLK + b] = hist[q];
}

// 3-phase exclusive scan (generic n)
__global__ __launch_bounds__(256) void scanA_kernel(const int* __restrict__ deg,
                                                    int* __restrict__ blk, int n) {
    __shared__ int red[4];
    const int i = blockIdx.x * 256 + threadIdx.x;
    int v = (i < n) ? deg[i] : 0;
    #pragma unroll
    for (int off = 32; off > 0; off >>= 1) v += __shfl_xor(v, off);
    if ((threadIdx.x & 63) == 0) red[threadIdx.x >> 6] = v;
    __syncthreads();
    if (threadIdx.x == 0) blk[blockIdx.x] = red[0] + red[1] + red[2] + red[3];
}

__global__ __launch_bounds__(256) void scanB_kernel(int* __restrict__ blk, int nb) {
    __shared__ int s[256];
    const int t = threadIdx.x;
    const int v = (t < nb) ? blk[t] : 0;
    s[t] = v;
    __syncthreads();
    for (int off = 1; off < 256; off <<= 1) {
        int u = (t >= off) ? s[t - off] : 0;
        __syncthreads();
        s[t] += u;
        __syncthreads();
    }
    if (t < nb) blk[t] = s[t] - v;  // exclusive
}

__global__ __launch_bounds__(256) void scanC_kernel(const int* __restrict__ deg,
                                                    const int* __restrict__ blk,
                                                    int* __restrict__ out, int n) {
    __shared__ int s[256];
    const int t = threadIdx.x;
    const int i = blockIdx.x * 256 + t;
    const int v = (i < n) ? deg[i] : 0;
    s[t] = v;
    __syncthreads();
    for (int off = 1; off < 256; off <<= 1) {
        int u = (t >= off) ? s[t - off] : 0;
        __syncthreads();
        s[t] += u;
        __syncthreads();
    }
    if (i <= n) out[i] = blk[blockIdx.x] + s[t] - v;
}

__global__ __launch_bounds__(256) void bscatter_kernel(const int* __restrict__ src,
                                                       const int* __restrict__ dst,
                                                       const int* __restrict__ roff,
                                                       unsigned* __restrict__ ebuf, int E) {
    __shared__ int cur[NBUCK];
    const int b = blockIdx.x;
    for (int q = threadIdx.x; q < NBUCK; q += 256) cur[q] = roff[q * NBLK + b];
    __syncthreads();
    const int e0 = b * EPB;
    const int e1 = min(e0 + EPB, E);
    for (int e = e0 + threadIdx.x; e < e1; e += 256) {
        const int d = dst[e];
        const int pos = atomicAdd(&cur[d >> 8], 1);
        ebuf[pos] = ((unsigned)(d & 255) << 16) | (unsigned)src[e];
    }
}

// one block per bucket: local CSR (contiguous csr region per bucket -> XCD-local writes)
__global__ __launch_bounds__(256) void bcsr_kernel(const unsigned* __restrict__ ebuf,
                                                   const int* __restrict__ roff,
                                                   int* __restrict__ csr_src,
                                                   int* __restrict__ row_ptr,
                                                   float* __restrict__ invd) {
    __shared__ int degs[256];
    __shared__ int scn[256];
    __shared__ int cur[256];
    const int q = blockIdx.x;
    const int t = threadIdx.x;
    const int start = roff[q * NBLK];
    const int end = (q == NBUCK - 1) ? NE : roff[(q + 1) * NBLK];
    degs[t] = 0;
    __syncthreads();
    for (int e = start + t; e < end; e += 256)
        atomicAdd(&degs[ebuf[e] >> 16], 1);
    __syncthreads();
    const int v = degs[t];
    scn[t] = v;
    __syncthreads();
    for (int off = 1; off < 256; off <<= 1) {
        int u = (t >= off) ? scn[t - off] : 0;
        __syncthreads();
        scn[t] += u;
        __syncthreads();
    }
    const int excl = scn[t] - v;
    cur[t] = start + excl;
    __syncthreads();
    for (int e = start + t; e < end; e += 256) {
        const unsigned p = ebuf[e];
        const int pos = atomicAdd(&cur[p >> 16], 1);
        csr_src[pos] = (int)(p & 0xffffu);
    }
    const int node = q * 256 + t;
    if (node < NN) {
        row_ptr[node] = start + excl;
        invd[node] = 1.0f / fmaxf((float)v, 1.0f);
    }
    if (q == NBUCK - 1 && t == 0) row_ptr[NN] = NE;
}

// ---------------- converts ----------------
__global__ void cvt_x_kernel(const float* __restrict__ in, ushort* __restrict__ outb,
                             unsigned* __restrict__ out8, int n4) {
    int i = blockIdx.x * blockDim.x + threadIdx.x;
    if (i >= n4) return;
    const float4 v = *reinterpret_cast<const float4*>(in + (size_t)i * 4);
    ushort4 o;
    o.x = f2b(v.x); o.y = f2b(v.y); o.z = f2b(v.z); o.w = f2b(v.w);
    *reinterpret_cast<ushort4*>(outb + (size_t)i * 4) = o;
    unsigned p = __builtin_amdgcn_cvt_pk_fp8_f32(v.x, v.y, 0, 0);
    p = __builtin_amdgcn_cvt_pk_fp8_f32(v.z, v.w, p, 1);
    out8[i] = p;
}

// in: [nmat][256][ncol] f32  ->  out: [nmat][ncol][256] bf16 (transposed per matrix)
__global__ void cvt_wt_kernel(const float* __restrict__ in, ushort* __restrict__ out,
                              int nmat, int ncol) {
    int idx = blockIdx.x * blockDim.x + threadIdx.x;
    int total = nmat * 256 * ncol;
    if (idx >= total) return;
    int k = idx & 255;
    int t = idx >> 8;
    int n = t % ncol;
    int m = t / ncol;
    out[idx] = f2b(in[(size_t)m * 256 * ncol + (size_t)k * ncol + n]);
}

// ---------------- gather-mean over fp8 rows: one wave per node, 16 neighbors in flight ------
__global__ __launch_bounds__(256) void gather_kernel(const unsigned char* __restrict__ h8,
                                                     const int* __restrict__ csr_src,
                                                     const int* __restrict__ row_ptr,
                                                     const float* __restrict__ invd,
                                                     ushort* __restrict__ agg, int n) {
    const int node = blockIdx.x * 4 + (threadIdx.x >> 6);
    const int lane = threadIdx.x & 63;
    if (node >= n) return;
    const int beg = row_ptr[node];
    const int end = row_ptr[node + 1];
    const int g = lane >> 4;
    const int l16 = lane & 15;

    float a[16];
    #pragma unroll
    for (int j = 0; j < 16; ++j) a[j] = 0.f;

    int i = beg;
    for (; i + 15 < end; i += 16) {
        const int s0 = csr_src[i + g];
        const int s1 = csr_src[i + 4 + g];
        const int s2 = csr_src[i + 8 + g];
        const int s3 = csr_src[i + 12 + g];
        const uint4 v0 = *reinterpret_cast<const uint4*>(h8 + (size_t)s0 * D + l16 * 16);
        const uint4 v1 = *reinterpret_cast<const uint4*>(h8 + (size_t)s1 * D + l16 * 16);
        const uint4 v2 = *reinterpret_cast<const uint4*>(h8 + (size_t)s2 * D + l16 * 16);
        const uint4 v3 = *reinterpret_cast<const uint4*>(h8 + (size_t)s3 * D + l16 * 16);
        const unsigned w[16] = {v0.x, v0.y, v0.z, v0.w, v1.x, v1.y, v1.z, v1.w,
                                v2.x, v2.y, v2.z, v2.w, v3.x, v3.y, v3.z, v3.w};
        #pragma unroll
        for (int q = 0; q < 16; ++q) {
            const f32x2 lo = __builtin_amdgcn_cvt_pk_f32_fp8(w[q], 0);
            const f32x2 hi = __builtin_amdgcn_cvt_pk_f32_fp8(w[q], 1);
            const int b = (q & 3) * 4;
            a[b + 0] += lo.x; a[b + 1] += lo.y; a[b + 2] += hi.x; a[b + 3] += hi.y;
        }
    }
    #pragma unroll
    for (int t = 0; t < 4; ++t) {
        const int idx = i + 4 * t + g;
        if (idx < end) {
            const int s = csr_src[idx];
            const uint4 v = *reinterpret_cast<const uint4*>(h8 + (size_t)s * D + l16 * 16);
            const unsigned w[4] = {v.x, v.y, v.z, v.w};
            #pragma unroll
            for (int q = 0; q < 4; ++q) {
                const f32x2 lo = __builtin_amdgcn_cvt_pk_f32_fp8(w[q], 0);
                const f32x2 hi = __builtin_amdgcn_cvt_pk_f32_fp8(w[q], 1);
                a[4 * q + 0] += lo.x; a[4 * q + 1] += lo.y;
                a[4 * q + 2] += hi.x; a[4 * q + 3] += hi.y;
            }
        }
    }
    #pragma unroll
    for (int j = 0; j < 16; ++j) {
        a[j] += __shfl_xor(a[j], 16);
        a[j] += __shfl_xor(a[j], 32);
    }
    if (g == 0) {
        const float sc = invd[node];
        ushort tmp[16];
        #pragma unroll
        for (int j = 0; j < 16; ++j) tmp[j] = f2b(a[j] * sc);
        ushort* w = agg + (size_t)node * D + l16 * 16;
        *reinterpret_cast<u16x8*>(w)     = *reinterpret_cast<u16x8*>(&tmp[0]);
        *reinterpret_cast<u16x8*>(w + 8) = *reinterpret_cast<u16x8*>(&tmp[8]);
    }
}

// ---------------- bf16 MFMA GEMM, 128 rows x 256 cols per block, 512 threads ----------------
template <bool DUAL, bool RELU, bool OUTBF, bool OUT8>
__global__ __launch_bounds__(512) void mgemm256_kernel(
    const ushort* __restrict__ A0, const ushort* __restrict__ A1,
    const ushort* __restrict__ B0T, const ushort* __restrict__ B1T,
    const float* __restrict__ bias, void* __restrict__ out,
    unsigned char* __restrict__ out8, int N)
{
    __shared__ ushort As[128][40];
    __shared__ ushort Bs[256][40];

    const int tid = threadIdx.x;
    const int wave = tid >> 6;
    const int lane = tid & 63;
    const int wm = wave >> 2;
    const int wn = wave & 3;
    const int l15 = lane & 15;
    const int l4 = lane >> 4;
    const int r0 = blockIdx.x * 128;

    const f32x4 zero = {0.f, 0.f, 0.f, 0.f};
    f32x4 acc[4][4];
    #pragma unroll
    for (int i = 0; i < 4; ++i)
        #pragma unroll
        for (int j = 0; j < 4; ++j) acc[i][j] = zero;

    const int arr = tid >> 2;
    const int ach = (tid & 3) * 8;
    const int agrow = min(r0 + arr, N - 1);

    const int NT = DUAL ? 16 : 8;
    for (int kt = 0; kt < NT; ++kt) {
        const bool second = DUAL && (kt >= 8);
        const ushort* A = second ? A1 : A0;
        const ushort* BT = second ? B1T : B0T;
        const int kb = (second ? (kt - 8) : kt) * 32;

        *reinterpret_cast<float4*>(&As[arr][ach]) =
            *reinterpret_cast<const float4*>(A + (size_t)agrow * 256 + kb + ach);
        #pragma unroll
        for (int it = 0; it < 2; ++it) {
            const int idx = it * 512 + tid;
            const int br = idx >> 2;
            const int ch = (idx & 3) * 8;
            *reinterpret_cast<float4*>(&Bs[br][ch]) =
                *reinterpret_cast<const float4*>(BT + (size_t)br * 256 + kb + ch);
        }
        __syncthreads();

        bf16x8 af[4], bfr[4];
        #pragma unroll
        for (int i = 0; i < 4; ++i)
            af[i] = *reinterpret_cast<const bf16x8*>(&As[wm * 64 + 16 * i + l15][l4 * 8]);
        #pragma unroll
        for (int j = 0; j < 4; ++j)
            bfr[j] = *reinterpret_cast<const bf16x8*>(&Bs[wn * 64 + 16 * j + l15][l4 * 8]);
        #pragma unroll
        for (int i = 0; i < 4; ++i)
            #pragma unroll
            for (int j = 0; j < 4; ++j)
                acc[i][j] = __builtin_amdgcn_mfma_f32_16x16x32_bf16(af[i], bfr[j], acc[i][j], 0, 0, 0);
        __syncthreads();
    }

    const int rbase = r0 + wm * 64;
    const int cbase = wn * 64;
    #pragma unroll
    for (int i = 0; i < 4; ++i) {
        #pragma unroll
        for (int r = 0; r < 4; ++r) {
            const int row = rbase + 16 * i + l4 * 4 + r;
            if (row < N) {
                #pragma unroll
                for (int j = 0; j < 4; ++j) {
                    const int col = cbase + 16 * j + l15;
                    float v = acc[i][j][r] + bias[col];
                    if (RELU) v = fmaxf(v, 0.f);
                    if (OUTBF)
                        ((ushort*)out)[(size_t)row * 256 + col] = f2b(v);
                    else
                        ((float*)out)[(size_t)row * 256 + col] = v;
                    if (OUT8)
                        out8[(size_t)row * 256 + col] = f2fp8(v);
                }
            }
        }
    }
}

// ---------------- final GEMM (128 cols) with fused log-softmax ----------------
__global__ __launch_bounds__(256) void mgemm128sm_kernel(
    const ushort* __restrict__ A0, const ushort* __restrict__ B0T,
    const float* __restrict__ bias, float* __restrict__ out, int N)
{
    __shared__ ushort As[128][40];
    __shared__ ushort Bs[128][40];
    __shared__ float msh[2][128];
    __shared__ float ssh[2][128];

    const int tid = threadIdx.x;
    const int wave = tid >> 6;
    const int lane = tid & 63;
    const int wm = wave >> 1;
    const int wn = wave & 1;
    const int l15 = lane & 15;
    const int l4 = lane >> 4;
    const int r0 = blockIdx.x * 128;

    const f32x4 zero = {0.f, 0.f, 0.f, 0.f};
    f32x4 acc[4][4];
    #pragma unroll
    for (int i = 0; i < 4; ++i)
        #pragma unroll
        for (int j = 0; j < 4; ++j) acc[i][j] = zero;

    for (int kt = 0; kt < 8; ++kt) {
        const int kb = kt * 32;
        #pragma unroll
        for (int it = 0; it < 2; ++it) {
            const int idx = it * 256 + tid;
            const int rr = idx >> 2;
            const int ch = (idx & 3) * 8;
            const int grow = min(r0 + rr, N - 1);
            *reinterpret_cast<float4*>(&As[rr][ch]) =
                *reinterpret_cast<const float4*>(A0 + (size_t)grow * 256 + kb + ch);
            *reinterpret_cast<float4*>(&Bs[rr][ch]) =
                *reinterpret_cast<const float4*>(B0T + (size_t)rr * 256 + kb + ch);
        }
        __syncthreads();

        bf16x8 af[4], bfr[4];
        #pragma unroll
        for (int i = 0; i < 4; ++i)
            af[i] = *reinterpret_cast<const bf16x8*>(&As[wm * 64 + 16 * i + l15][l4 * 8]);
        #pragma unroll
        for (int j = 0; j < 4; ++j)
            bfr[j] = *reinterpret_cast<const bf16x8*>(&Bs[wn * 64 + 16 * j + l15][l4 * 8]);
        #pragma unroll
        for (int i = 0; i < 4; ++i)
            #pragma unroll
            for (int j = 0; j < 4; ++j)
                acc[i][j] = __builtin_amdgcn_mfma_f32_16x16x32_bf16(af[i], bfr[j], acc[i][j], 0, 0, 0);
        __syncthreads();
    }

    const int cbase = wn * 64;
    float bb[4];
    #pragma unroll
    for (int j = 0; j < 4; ++j) bb[j] = bias[cbase + 16 * j + l15];

    #pragma unroll
    for (int i = 0; i < 4; ++i) {
        #pragma unroll
        for (int r = 0; r < 4; ++r) {
            float v0 = acc[i][0][r] + bb[0];
            float v1 = acc[i][1][r] + bb[1];
            float v2 = acc[i][2][r] + bb[2];
            float v3 = acc[i][3][r] + bb[3];
            float m = fmaxf(fmaxf(v0, v1), fmaxf(v2, v3));
            #pragma unroll
            for (int off = 8; off > 0; off >>= 1) m = fmaxf(m, __shfl_xor(m, off));
            float s = expf(v0 - m) + expf(v1 - m) + expf(v2 - m) + expf(v3 - m);
            #pragma unroll
            for (int off = 8; off > 0; off >>= 1) s += __shfl_xor(s, off);
            if (l15 == 0) {
                const int lr = wm * 64 + 16 * i + l4 * 4 + r;
                msh[wn][lr] = m;
                ssh[wn][lr] = s;
            }
        }
    }
    __syncthreads();

    #pragma unroll
    for (int i = 0; i < 4; ++i) {
        #pragma unroll
        for (int r = 0; r < 4; ++r) {
            const int lr = wm * 64 + 16 * i + l4 * 4 + r;
            const float m0 = msh[0][lr], m1 = msh[1][lr];
            const float s0 = ssh[0][lr], s1 = ssh[1][lr];
            const float M = fmaxf(m0, m1);
            const float ls = M + logf(s0 * expf(m0 - M) + s1 * expf(m1 - M));
            const int row = r0 + lr;
            if (row < N) {
                #pragma unroll
                for (int j = 0; j < 4; ++j)
                    out[(size_t)row * DOUT + cbase + 16 * j + l15] = acc[i][j][r] + bb[j] - ls;
            }
        }
    }
}

extern "C" void kernel_launch(void* const* d_in, const int* in_sizes, int n_in,
                              void* d_out, int out_size, void* d_ws, size_t ws_size,
                              hipStream_t stream) {
    const float* x  = (const float*)d_in[0];
    const int* ei   = (const int*)d_in[1];
    const float* wl = (const float*)d_in[2];
    const float* bl = (const float*)d_in[3];
    const float* wr = (const float*)d_in[4];
    const float* w1 = (const float*)d_in[5];
    const float* b1 = (const float*)d_in[6];
    const float* w2 = (const float*)d_in[7];
    const float* b2 = (const float*)d_in[8];
    const int* src = ei;
    const int* dst = ei + NE;

    // ---- workspace layout ----
    ushort* hx   = (ushort*)d_ws;                 // NN*D bf16
    ushort* hA   = hx + (size_t)NN * D;
    ushort* hB   = hA + (size_t)NN * D;
    ushort* aggb = hB + (size_t)NN * D;
    ushort* wlT  = aggb + (size_t)NN * D;         // 3*256*256
    ushort* wrT  = wlT + 3 * 256 * 256;
    ushort* w1T  = wrT + 3 * 256 * 256;
    ushort* w2T  = w1T + 256 * 256;               // 128*256
    unsigned char* h8x = (unsigned char*)(w2T + 128 * 256);  // NN*D fp8
    unsigned char* h8A = h8x + (size_t)NN * D;
    unsigned char* h8B = h8A + (size_t)NN * D;
    float* invd  = (float*)(h8B + (size_t)NN * D);  // NN
    int* row_ptr = (int*)(invd + NN);               // NN+1
    int* csr_src = row_ptr + NN + 1;                // NE
    unsigned* ebuf = (unsigned*)(csr_src + NE);     // NE
    int* gcnt    = (int*)(ebuf + NE);               // NSCAN
    int* roff    = gcnt + NSCAN;                    // NSCAN+1
    int* blk     = roff + NSCAN + 1;                // 256
    float* outf  = (float*)d_out;

    // ---- CSR build (counting sort, XCD-local writes) ----
    const int NSB = (NSCAN + 256) / 256;  // 77
    bcount_kernel<<<NBLK, 256, 0, stream>>>(dst, gcnt, NE);
    scanA_kernel<<<NSB, 256, 0, stream>>>(gcnt, blk, NSCAN);
    scanB_kernel<<<1, 256, 0, stream>>>(blk, NSB);
    scanC_kernel<<<NSB, 256, 0, stream>>>(gcnt, blk, roff, NSCAN);
    bscatter_kernel<<<NBLK, 256, 0, stream>>>(src, dst, roff, ebuf, NE);
    bcsr_kernel<<<NBUCK, 256, 0, stream>>>(ebuf, roff, csr_src, row_ptr, invd);

    // ---- converts ----
    cvt_x_kernel<<<(NN * D / 4 + 255) / 256, 256, 0, stream>>>(x, hx, (unsigned*)h8x, NN * D / 4);
    cvt_wt_kernel<<<(3 * 256 * 256 + 255) / 256, 256, 0, stream>>>(wl, wlT, 3, 256);
    cvt_wt_kernel<<<(3 * 256 * 256 + 255) / 256, 256, 0, stream>>>(wr, wrT, 3, 256);
    cvt_wt_kernel<<<(256 * 256 + 255) / 256, 256, 0, stream>>>(w1, w1T, 1, 256);
    cvt_wt_kernel<<<(128 * 256 + 255) / 256, 256, 0, stream>>>(w2, w2T, 1, 128);

    const int gpan = (NN + 127) / 128;
    const int gg = (NN + 3) / 4;

    // layer 0
    gather_kernel<<<gg, 256, 0, stream>>>(h8x, csr_src, row_ptr, invd, aggb, NN);
    mgemm256_kernel<true, true, true, true><<<gpan, 512, 0, stream>>>(
        aggb, hx, wlT, wrT, bl, hA, h8A, NN);
    // layer 1
    gather_kernel<<<gg, 256, 0, stream>>>(h8A, csr_src, row_ptr, invd, aggb, NN);
    mgemm256_kernel<true, true, true, true><<<gpan, 512, 0, stream>>>(
        aggb, hA, wlT + 256 * 256, wrT + 256 * 256, bl + 256, hB, h8B, NN);
    // layer 2
    gather_kernel<<<gg, 256, 0, stream>>>(h8B, csr_src, row_ptr, invd, aggb, NN);
    mgemm256_kernel<true, true, true, false><<<gpan, 512, 0, stream>>>(
        aggb, hB, wlT + 2 * 256 * 256, wrT + 2 * 256 * 256, bl + 2 * 256, hA, nullptr, NN);
    // post-mp
    mgemm256_kernel<false, false, true, false><<<gpan, 512, 0, stream>>>(
        hA, nullptr, w1T, nullptr, b1, hB, nullptr, NN);
    mgemm128sm_kernel<<<gpan, 256, 0, stream>>>(hB, w2T, b2, outf, NN);
}